// Round 5
// baseline (305.596 us; speedup 1.0000x reference)
//
#include <hip/hip_runtime.h>
#include <hip/hip_bf16.h>

#define NROWS 8192
#define SD 512
#define FDIM 128
#define KNN 10
#define K2 11
#define C_CONST 1.0e-3f
#define L_CONST 5.0f
#define EPS_CONST 1.0e-3f
#define BIGF 3.0e38f
#define BCAP 17
#define TRIG 13
#define NSEG 32

typedef float f32x4 __attribute__((ext_vector_type(4)));
typedef __bf16 bf16x8 __attribute__((ext_vector_type(8)));
typedef unsigned short ushort4v __attribute__((ext_vector_type(4)));
typedef unsigned short ushort8v __attribute__((ext_vector_type(8)));

__device__ __forceinline__ unsigned short f32_to_bf16_rne(float f) {
    unsigned int x = __float_as_uint(f);
    unsigned int lsb = (x >> 16) & 1u;
    x += 0x7fffu + lsb;
    return (unsigned short)(x >> 16);
}

__device__ __forceinline__ void split_bf16(float v, unsigned short& h, unsigned short& l) {
    unsigned short hh = f32_to_bf16_rne(v);
    float hf = __uint_as_float(((unsigned int)hh) << 16);
    h = hh;
    l = f32_to_bf16_rne(v - hf);
}

__device__ __forceinline__ void insert11(float* v, float tv) {
    #pragma unroll
    for (int u = 0; u < K2; ++u) {
        float lo = fminf(v[u], tv);
        tv = fmaxf(v[u], tv);
        v[u] = lo;
    }
}

__device__ __forceinline__ void compactB(float* v, const float* bp, int cnt) {
    #pragma unroll
    for (int i = 0; i < 16; ++i) {
        float tv = (i < cnt) ? bp[i] : BIGF;
        insert11(v, tv);
    }
}

__device__ __forceinline__ void ce(float& a, float& b) {
    float lo = fminf(a, b), hi = fmaxf(a, b); a = lo; b = hi;
}
// sort an 11-elem bitonic sequence ascending: clipped 16-wire bitonic merge (17 CE)
__device__ __forceinline__ void sortBitonic11(float* w) {
    ce(w[0],w[8]); ce(w[1],w[9]); ce(w[2],w[10]);
    ce(w[0],w[4]); ce(w[1],w[5]); ce(w[2],w[6]); ce(w[3],w[7]);
    ce(w[0],w[2]); ce(w[1],w[3]); ce(w[4],w[6]); ce(w[5],w[7]); ce(w[8],w[10]);
    ce(w[0],w[1]); ce(w[2],w[3]); ce(w[4],w[5]); ce(w[6],w[7]); ce(w[8],w[9]);
}

// ---------------- K0: prep (s hi/lo split + weight concat/pad/split) ----------------
__global__ __launch_bounds__(256) void k_prep(
    const float* __restrict__ s,
    const float* __restrict__ w1, const float* __restrict__ wt1, const float* __restrict__ wz1,
    const float* __restrict__ w2, const float* __restrict__ wt2, const float* __restrict__ wz2,
    const float* __restrict__ w3, const float* __restrict__ wt3, const float* __restrict__ wz3,
    const float* __restrict__ b1, const float* __restrict__ bt1, const float* __restrict__ bz1,
    const float* __restrict__ b2, const float* __restrict__ bt2, const float* __restrict__ bz2,
    const float* __restrict__ b3, const float* __restrict__ bt3, const float* __restrict__ bz3,
    unsigned short* __restrict__ sh, unsigned short* __restrict__ sl,
    unsigned short* __restrict__ w1h, unsigned short* __restrict__ w1l,
    unsigned short* __restrict__ w2h, unsigned short* __restrict__ w2l,
    unsigned short* __restrict__ w3h, unsigned short* __restrict__ w3l,
    float* __restrict__ b1c, float* __restrict__ b2c, float* __restrict__ b3c)
{
    const int b = blockIdx.x;
    const int t = threadIdx.x;
    if (b < 2048) {
        // split s: 8 elems per thread
        size_t base = ((size_t)b * 256 + t) * 8;
        f32x4 a = *(const f32x4*)(s + base);
        f32x4 c = *(const f32x4*)(s + base + 4);
        ushort8v h, l;
        #pragma unroll
        for (int j = 0; j < 4; ++j) {
            unsigned short hh, ll;
            split_bf16(a[j], hh, ll); h[j] = hh; l[j] = ll;
            split_bf16(c[j], hh, ll); h[4 + j] = hh; l[4 + j] = ll;
        }
        *(ushort8v*)(sh + base) = h;
        *(ushort8v*)(sl + base) = l;
    } else if (b < 2240) {
        int idx = ((b - 2048) * 256 + t) * 4;
        int n = idx >> 9, k = idx & 511;
        const float* src = (n < 128) ? (w1 + (size_t)n * 512)
                         : (n < 256) ? (wt1 + (size_t)(n - 128) * 512)
                                     : (wz1 + (size_t)(n - 256) * 512);
        f32x4 v = *(const f32x4*)(src + k);
        ushort4v h, l;
        #pragma unroll
        for (int j = 0; j < 4; ++j) { unsigned short hh, ll; split_bf16(v[j], hh, ll); h[j] = hh; l[j] = ll; }
        *(ushort4v*)(w1h + idx) = h;
        *(ushort4v*)(w1l + idx) = l;
    } else if (b < 2312) {
        int idx = ((b - 2240) * 256 + t) * 4;
        int n = idx / 384, k = idx % 384;
        f32x4 v = {0.f, 0.f, 0.f, 0.f};
        if (n < 64)       { if (k < 128)             v = *(const f32x4*)(w2  + (size_t)n * 128 + k); }
        else if (n < 128) { if (k >= 128 && k < 256) v = *(const f32x4*)(wt2 + (size_t)(n - 64) * 128 + (k - 128)); }
        else              { if (k >= 256)            v = *(const f32x4*)(wz2 + (size_t)(n - 128) * 128 + (k - 256)); }
        ushort4v h, l;
        #pragma unroll
        for (int j = 0; j < 4; ++j) { unsigned short hh, ll; split_bf16(v[j], hh, ll); h[j] = hh; l[j] = ll; }
        *(ushort4v*)(w2h + idx) = h;
        *(ushort4v*)(w2l + idx) = l;
    } else if (b < 2339) {
        int idx = ((b - 2312) * 256 + t) * 4;
        int n = idx / 192, k = idx % 192;
        f32x4 v = {0.f, 0.f, 0.f, 0.f};
        if (n == 0)                 { if (k < 64)             v = *(const f32x4*)(w3 + k); }
        else if (n == 1)            { if (k >= 64 && k < 128) v = *(const f32x4*)(wt3 + (k - 64)); }
        else if (n >= 16 && n < 144){ if (k >= 128)           v = *(const f32x4*)(wz3 + (size_t)(n - 16) * 64 + (k - 128)); }
        ushort4v h, l;
        #pragma unroll
        for (int j = 0; j < 4; ++j) { unsigned short hh, ll; split_bf16(v[j], hh, ll); h[j] = hh; l[j] = ll; }
        *(ushort4v*)(w3h + idx) = h;
        *(ushort4v*)(w3l + idx) = l;
    } else {
        for (int i = t; i < 720; i += 256) {
            if (i < 384)      b1c[i] = (i < 128) ? b1[i] : (i < 256) ? bt1[i - 128] : bz1[i - 256];
            else if (i < 576) { int j = i - 384; b2c[j] = (j < 64) ? b2[j] : (j < 128) ? bt2[j - 64] : bz2[j - 128]; }
            else              { int j = i - 576; b3c[j] = (j == 0) ? b3[0] : (j == 1) ? bt3[0] : (j < 16) ? 0.f : bz3[j - 16]; }
        }
    }
}

// ---------------- GEMM1: h1 = relu(s @ W1cat^T + b1c) ----------------
// 1024 blocks x 256 thr; block: ng = b&7 (shared by 4 waves -> L1 weight reuse),
// m-tile = (b>>3)*4 + wave. Wave-tile: 16 rows x 48 cols.
__global__ __launch_bounds__(256, 4) void k_gemm1(
    const unsigned short* __restrict__ xh_, const unsigned short* __restrict__ xl_,
    const unsigned short* __restrict__ wh, const unsigned short* __restrict__ wl,
    const float* __restrict__ bias,
    unsigned short* __restrict__ outh, unsigned short* __restrict__ outl)
{
    const int t = threadIdx.x;
    const int lane = t & 63, wv = t >> 6;
    const int l15 = lane & 15, lg = lane >> 4;
    const int ng = blockIdx.x & 7;
    const int mt = (blockIdx.x >> 3) * 4 + wv;
    const int m = mt * 16 + l15;
    const int nbase = ng * 3;

    f32x4 acc[3];
    #pragma unroll
    for (int i = 0; i < 3; ++i) acc[i] = (f32x4){0.f, 0.f, 0.f, 0.f};

    const unsigned short* xh = xh_ + (size_t)m * 512;
    const unsigned short* xl = xl_ + (size_t)m * 512;
    for (int kt = 0; kt < 16; ++kt) {
        const int k0 = kt * 32 + lg * 8;
        bf16x8 axh = *(const bf16x8*)(xh + k0);
        bf16x8 axl = *(const bf16x8*)(xl + k0);
        #pragma unroll
        for (int i = 0; i < 3; ++i) {
            const size_t off = (size_t)((nbase + i) * 16 + l15) * 512 + k0;
            bf16x8 bh = *(const bf16x8*)(wh + off);
            bf16x8 bl = *(const bf16x8*)(wl + off);
            acc[i] = __builtin_amdgcn_mfma_f32_16x16x32_bf16(bh, axh, acc[i], 0, 0, 0);
            acc[i] = __builtin_amdgcn_mfma_f32_16x16x32_bf16(bl, axh, acc[i], 0, 0, 0);
            acc[i] = __builtin_amdgcn_mfma_f32_16x16x32_bf16(bh, axl, acc[i], 0, 0, 0);
        }
    }
    #pragma unroll
    for (int i = 0; i < 3; ++i) {
        const int n0 = (nbase + i) * 16 + lg * 4;
        f32x4 bv = *(const f32x4*)(bias + n0);
        f32x4 v = acc[i] + bv;
        ushort4v vh, vl;
        #pragma unroll
        for (int r = 0; r < 4; ++r) {
            float x = fmaxf(v[r], 0.f);
            unsigned short hh, ll; split_bf16(x, hh, ll);
            vh[r] = hh; vl[r] = ll;
        }
        *(ushort4v*)(outh + (size_t)m * 384 + n0) = vh;
        *(ushort4v*)(outl + (size_t)m * 384 + n0) = vl;
    }
}

// ---------------- GEMM2: h2 = relu(h1 @ W2cat^T + b2c) ----------------
// 768 blocks; ng = b%6 (32 cols), mt = (b/6)*4 + wave
__global__ __launch_bounds__(256, 4) void k_gemm2(
    const unsigned short* __restrict__ xh_, const unsigned short* __restrict__ xl_,
    const unsigned short* __restrict__ wh, const unsigned short* __restrict__ wl,
    const float* __restrict__ bias,
    unsigned short* __restrict__ outh, unsigned short* __restrict__ outl)
{
    const int t = threadIdx.x;
    const int lane = t & 63, wv = t >> 6;
    const int l15 = lane & 15, lg = lane >> 4;
    const int ng = blockIdx.x % 6;
    const int mt = (blockIdx.x / 6) * 4 + wv;
    const int m = mt * 16 + l15;
    const int nbase = ng * 2;

    f32x4 acc[2];
    #pragma unroll
    for (int i = 0; i < 2; ++i) acc[i] = (f32x4){0.f, 0.f, 0.f, 0.f};

    const unsigned short* xh = xh_ + (size_t)m * 384;
    const unsigned short* xl = xl_ + (size_t)m * 384;
    for (int kt = 0; kt < 12; ++kt) {
        const int k0 = kt * 32 + lg * 8;
        bf16x8 axh = *(const bf16x8*)(xh + k0);
        bf16x8 axl = *(const bf16x8*)(xl + k0);
        #pragma unroll
        for (int i = 0; i < 2; ++i) {
            const size_t off = (size_t)((nbase + i) * 16 + l15) * 384 + k0;
            bf16x8 bh = *(const bf16x8*)(wh + off);
            bf16x8 bl = *(const bf16x8*)(wl + off);
            acc[i] = __builtin_amdgcn_mfma_f32_16x16x32_bf16(bh, axh, acc[i], 0, 0, 0);
            acc[i] = __builtin_amdgcn_mfma_f32_16x16x32_bf16(bl, axh, acc[i], 0, 0, 0);
            acc[i] = __builtin_amdgcn_mfma_f32_16x16x32_bf16(bh, axl, acc[i], 0, 0, 0);
        }
    }
    #pragma unroll
    for (int i = 0; i < 2; ++i) {
        const int n0 = (nbase + i) * 16 + lg * 4;
        f32x4 bv = *(const f32x4*)(bias + n0);
        f32x4 v = acc[i] + bv;
        ushort4v vh, vl;
        #pragma unroll
        for (int r = 0; r < 4; ++r) {
            float x = fmaxf(v[r], 0.f);
            unsigned short hh, ll; split_bf16(x, hh, ll);
            vh[r] = hh; vl[r] = ll;
        }
        *(ushort4v*)(outh + (size_t)m * 192 + n0) = vh;
        *(ushort4v*)(outl + (size_t)m * 192 + n0) = vl;
    }
}

// ---------------- GEMM3: out144 = h2 @ W3cat^T + b3c; epilogue -> zb/sq(atomic)/alpha ----------------
// 384 blocks; ng = b%3 (48 cols), mt = (b/3)*4 + wave. sq must be pre-zeroed.
__global__ __launch_bounds__(256, 4) void k_gemm3(
    const unsigned short* __restrict__ xh_, const unsigned short* __restrict__ xl_,
    const unsigned short* __restrict__ wh, const unsigned short* __restrict__ wl,
    const float* __restrict__ bias,
    unsigned short* __restrict__ zb, float* __restrict__ sq, float* __restrict__ alpha)
{
    const int t = threadIdx.x;
    const int lane = t & 63, wv = t >> 6;
    const int l15 = lane & 15, lg = lane >> 4;
    const int ng = blockIdx.x % 3;
    const int mt = (blockIdx.x / 3) * 4 + wv;
    const int m = mt * 16 + l15;
    const int nbase = ng * 3;

    f32x4 acc[3];
    #pragma unroll
    for (int i = 0; i < 3; ++i) acc[i] = (f32x4){0.f, 0.f, 0.f, 0.f};

    const unsigned short* xh = xh_ + (size_t)m * 192;
    const unsigned short* xl = xl_ + (size_t)m * 192;
    for (int kt = 0; kt < 6; ++kt) {
        const int k0 = kt * 32 + lg * 8;
        bf16x8 axh = *(const bf16x8*)(xh + k0);
        bf16x8 axl = *(const bf16x8*)(xl + k0);
        #pragma unroll
        for (int i = 0; i < 3; ++i) {
            const size_t off = (size_t)((nbase + i) * 16 + l15) * 192 + k0;
            bf16x8 bh = *(const bf16x8*)(wh + off);
            bf16x8 bl = *(const bf16x8*)(wl + off);
            acc[i] = __builtin_amdgcn_mfma_f32_16x16x32_bf16(bh, axh, acc[i], 0, 0, 0);
            acc[i] = __builtin_amdgcn_mfma_f32_16x16x32_bf16(bl, axh, acc[i], 0, 0, 0);
            acc[i] = __builtin_amdgcn_mfma_f32_16x16x32_bf16(bh, axl, acc[i], 0, 0, 0);
        }
    }

    float ssq = 0.f;
    float pred = 0.f, tgt = 0.f;
    #pragma unroll
    for (int i = 0; i < 3; ++i) {
        const int ntg = nbase + i;
        const int n0 = ntg * 16 + lg * 4;
        f32x4 bv = *(const f32x4*)(bias + n0);
        f32x4 v = acc[i] + bv;
        if (ntg == 0) {
            if (lg == 0) { pred = v.x; tgt = v.y; }
        } else {
            ushort4v zu;
            #pragma unroll
            for (int r = 0; r < 4; ++r) {
                unsigned short us = f32_to_bf16_rne(v[r]);
                float zf = __uint_as_float(((unsigned int)us) << 16);
                ssq += zf * zf;
                zu[r] = us;
            }
            *(ushort4v*)(zb + (size_t)m * FDIM + (ntg - 1) * 16 + lg * 4) = zu;
        }
    }
    ssq += __shfl_xor(ssq, 16);
    ssq += __shfl_xor(ssq, 32);
    if (lg == 0) atomicAdd(sq + m, ssq);
    if (ng == 0 && lg == 0) {
        float d = pred - tgt;
        alpha[m] = d * d;
    }
}

// ---------------- K2: pairwise + threshold-filtered top-11 ----------------
// 4096 blocks x 256 thr; split = b&31 (shared by 4 waves), qg16 = (b>>5)*4 + wave.
// Wave: 16 queries x 256 candidates (16 tiles). Self excluded later via drop-min.
__global__ __launch_bounds__(256, 4) void k_pairs(
    const unsigned short* __restrict__ zb, const float* __restrict__ sq,
    float* __restrict__ part)
{
    __shared__ float buf[4][64][BCAP];
    __shared__ float sqs[256];
    const int t = threadIdx.x;
    const int lane = t & 63, wv = t >> 6;
    const int split = blockIdx.x & 31;
    const int qg16 = (blockIdx.x >> 5) * 4 + wv;
    const int l15 = lane & 15, lg = lane >> 4;
    const int c0 = split * 256;

    sqs[t] = sq[c0 + t];
    __syncthreads();

    float* bp = &buf[wv][lane][0];
    const int qid = qg16 * 16 + l15;
    const unsigned short* qp = zb + (size_t)qid * FDIM + lg * 8;
    bf16x8 bq0 = *(const bf16x8*)(qp);
    bf16x8 bq1 = *(const bf16x8*)(qp + 32);
    bf16x8 bq2 = *(const bf16x8*)(qp + 64);
    bf16x8 bq3 = *(const bf16x8*)(qp + 96);

    float vals[K2];
    #pragma unroll
    for (int i = 0; i < K2; ++i) vals[i] = BIGF;
    float thr = BIGF;
    int cnt = 0;

    const unsigned short* ap = zb + (size_t)(c0 + l15) * FDIM + lg * 8;
    bf16x8 av0 = *(const bf16x8*)(ap);
    bf16x8 av1 = *(const bf16x8*)(ap + 32);
    bf16x8 av2 = *(const bf16x8*)(ap + 64);
    bf16x8 av3 = *(const bf16x8*)(ap + 96);

    for (int tile = 0; tile < 16; ++tile) {
        f32x4 acc = {0.f, 0.f, 0.f, 0.f};
        acc = __builtin_amdgcn_mfma_f32_16x16x32_bf16(av0, bq0, acc, 0, 0, 0);
        acc = __builtin_amdgcn_mfma_f32_16x16x32_bf16(av1, bq1, acc, 0, 0, 0);
        acc = __builtin_amdgcn_mfma_f32_16x16x32_bf16(av2, bq2, acc, 0, 0, 0);
        acc = __builtin_amdgcn_mfma_f32_16x16x32_bf16(av3, bq3, acc, 0, 0, 0);
        if (tile < 15) {
            const unsigned short* ap2 = zb + (size_t)(c0 + (tile + 1) * 16 + l15) * FDIM + lg * 8;
            av0 = *(const bf16x8*)(ap2);
            av1 = *(const bf16x8*)(ap2 + 32);
            av2 = *(const bf16x8*)(ap2 + 64);
            av3 = *(const bf16x8*)(ap2 + 96);
        }
        f32x4 sqv = *(const f32x4*)(&sqs[tile * 16 + lg * 4]);
        #pragma unroll
        for (int r = 0; r < 4; ++r) {
            float v = fmaf(-2.0f, acc[r], sqv[r]);   // key = dist^2 - sq_q (self = min)
            bp[cnt] = v;
            cnt += (int)(v < thr);
        }
        if (__any(cnt >= TRIG)) { compactB(vals, bp, cnt); thr = vals[K2 - 1]; cnt = 0; }
    }
    compactB(vals, bp, cnt);

    // cross-lane-group merge: ^16 min-trick -> bitonic sort -> ^32 min-trick
    float wk[K2];
    #pragma unroll
    for (int i = 0; i < K2; ++i) {
        float o = __shfl_xor(vals[K2 - 1 - i], 16);
        wk[i] = fminf(vals[i], o);
    }
    sortBitonic11(wk);
    float m1[K2];
    #pragma unroll
    for (int i = 0; i < K2; ++i) {
        float o = __shfl_xor(wk[K2 - 1 - i], 32);
        m1[i] = fminf(wk[i], o);
    }
    if (lg == 0) {
        float* dst = part + ((size_t)split * NROWS + qid) * K2;
        #pragma unroll
        for (int i = 0; i < K2; ++i) dst[i] = m1[i];
    }
}

// ---------------- K3: merge 32 partial 11-lists; drop min (self); sum 10 sqrt ----------------
__global__ __launch_bounds__(256) void k_merge(
    const float* __restrict__ part, const float* __restrict__ sq,
    float* __restrict__ sumk, float* __restrict__ total)
{
    const int q = blockIdx.x * 256 + threadIdx.x;
    float vals[K2];
    #pragma unroll
    for (int i = 0; i < K2; ++i) vals[i] = BIGF;
    for (int seg = 0; seg < NSEG; ++seg) {
        const float* p = part + ((size_t)seg * NROWS + q) * K2;
        #pragma unroll
        for (int i = 0; i < K2; ++i) {
            float tv = p[i];
            if (tv < vals[K2 - 1]) insert11(vals, tv);
        }
    }
    float sqq = sq[q];
    float sum = 0.f;
    #pragma unroll
    for (int i = 1; i < K2; ++i) {            // skip vals[0] = self
        float raw = sqq + vals[i];
        sum += (raw > 0.f) ? sqrtf(raw) : 0.f;
    }
    sumk[q] = sum;

    __shared__ float red[4];
    float bsum = sum;
    #pragma unroll
    for (int off = 32; off > 0; off >>= 1) bsum += __shfl_down(bsum, off);
    if ((threadIdx.x & 63) == 0) red[threadIdx.x >> 6] = bsum;
    __syncthreads();
    if (threadIdx.x == 0) atomicAdd(total, red[0] + red[1] + red[2] + red[3]);
}

// ---------------- K4: finalize ----------------
__global__ __launch_bounds__(256) void k_final(
    const float* __restrict__ sumk, const float* __restrict__ alpha,
    const float* __restrict__ total, float* __restrict__ out)
{
    const int q = blockIdx.x * 256 + threadIdx.x;
    float mean = (*total) * (1.0f / NROWS);
    float m2 = mean * mean;
    float sk = sumk[q];
    float x = (sk * sk) / m2;
    float knn = EPS_CONST / (x + EPS_CONST);
    float rep = 1.0f / (sqrtf(knn) + C_CONST);
    float a = alpha[q];
    a = fminf(fmaxf(a, 1.0f), L_CONST);
    out[q] = rep * a;
}

extern "C" void kernel_launch(void* const* d_in, const int* in_sizes, int n_in,
                              void* d_out, int out_size, void* d_ws, size_t ws_size,
                              hipStream_t stream) {
    const float* s   = (const float*)d_in[0];
    const float* w1  = (const float*)d_in[1];
    const float* b1  = (const float*)d_in[2];
    const float* w2  = (const float*)d_in[3];
    const float* b2  = (const float*)d_in[4];
    const float* w3  = (const float*)d_in[5];
    const float* b3  = (const float*)d_in[6];
    const float* wt1 = (const float*)d_in[7];
    const float* bt1 = (const float*)d_in[8];
    const float* wt2 = (const float*)d_in[9];
    const float* bt2 = (const float*)d_in[10];
    const float* wt3 = (const float*)d_in[11];
    const float* bt3 = (const float*)d_in[12];
    const float* wz1 = (const float*)d_in[13];
    const float* bz1 = (const float*)d_in[14];
    const float* wz2 = (const float*)d_in[15];
    const float* bz2 = (const float*)d_in[16];
    const float* wz3 = (const float*)d_in[17];
    const float* bz3 = (const float*)d_in[18];

    char* ws = (char*)d_ws;
    unsigned short* zb  = (unsigned short*)(ws);                // 2097152
    float* sq    = (float*)(ws + 2097152);                      // 32768
    float* alpha = (float*)(ws + 2129920);                      // 32768
    float* part  = (float*)(ws + 2162688);                      // 32*8192*11*4 = 11534336
    float* sumk  = (float*)(ws + 13697024);                     // 32768
    float* total = (float*)(ws + 13729792);                     // 256
    unsigned short* h1h = (unsigned short*)(ws + 13730048);     // 6291456
    unsigned short* h1l = (unsigned short*)(ws + 20021504);     // 6291456
    unsigned short* h2h = (unsigned short*)(ws + 26312960);     // 3145728
    unsigned short* h2l = (unsigned short*)(ws + 29458688);     // 3145728
    unsigned short* sh  = (unsigned short*)(ws + 32604416);     // 8388608
    unsigned short* sl  = (unsigned short*)(ws + 40993024);     // 8388608
    unsigned short* w1h = (unsigned short*)(ws + 49381632);     // 393216
    unsigned short* w1l = (unsigned short*)(ws + 49774848);     // 393216
    unsigned short* w2h = (unsigned short*)(ws + 50168064);     // 147456
    unsigned short* w2l = (unsigned short*)(ws + 50315520);     // 147456
    unsigned short* w3h = (unsigned short*)(ws + 50462976);     // 55296
    unsigned short* w3l = (unsigned short*)(ws + 50518272);     // 55296
    float* b1c = (float*)(ws + 50573568);
    float* b2c = (float*)(ws + 50575104);
    float* b3c = (float*)(ws + 50575872);

    hipMemsetAsync(total, 0, sizeof(float), stream);
    hipMemsetAsync(sq, 0, NROWS * sizeof(float), stream);

    k_prep<<<2340, 256, 0, stream>>>(s,
                                     w1, wt1, wz1, w2, wt2, wz2, w3, wt3, wz3,
                                     b1, bt1, bz1, b2, bt2, bz2, b3, bt3, bz3,
                                     sh, sl, w1h, w1l, w2h, w2l, w3h, w3l, b1c, b2c, b3c);
    k_gemm1<<<1024, 256, 0, stream>>>(sh, sl, w1h, w1l, b1c, h1h, h1l);
    k_gemm2<<<768, 256, 0, stream>>>(h1h, h1l, w2h, w2l, b2c, h2h, h2l);
    k_gemm3<<<384, 256, 0, stream>>>(h2h, h2l, w3h, w3l, b3c, zb, sq, alpha);
    k_pairs<<<4096, 256, 0, stream>>>(zb, sq, part);
    k_merge<<<32, 256, 0, stream>>>(part, sq, sumk, total);
    k_final<<<32, 256, 0, stream>>>(sumk, alpha, total, (float*)d_out);
}

// Round 6
// 199.423 us; speedup vs baseline: 1.5324x; 1.5324x over previous
//
#include <hip/hip_runtime.h>
#include <hip/hip_bf16.h>

#define NROWS 8192
#define SD 512
#define FDIM 128
#define KNN 10
#define K2 11
#define C_CONST 1.0e-3f
#define L_CONST 5.0f
#define EPS_CONST 1.0e-3f
#define BIGF 3.0e38f
#define BCAP 17
#define TRIG 13
#define NSEG 16

typedef float f32x4 __attribute__((ext_vector_type(4)));
typedef __bf16 bf16x8 __attribute__((ext_vector_type(8)));
typedef unsigned short ushort4v __attribute__((ext_vector_type(4)));
typedef unsigned short ushort8v __attribute__((ext_vector_type(8)));

__device__ __forceinline__ unsigned short f32_to_bf16_rne(float f) {
    unsigned int x = __float_as_uint(f);
    unsigned int lsb = (x >> 16) & 1u;
    x += 0x7fffu + lsb;
    return (unsigned short)(x >> 16);
}

__device__ __forceinline__ void split_bf16(float v, unsigned short& h, unsigned short& l) {
    unsigned short hh = f32_to_bf16_rne(v);
    float hf = __uint_as_float(((unsigned int)hh) << 16);
    h = hh;
    l = f32_to_bf16_rne(v - hf);
}

__device__ __forceinline__ void insert11(float* v, float tv) {
    #pragma unroll
    for (int u = 0; u < K2; ++u) {
        float lo = fminf(v[u], tv);
        tv = fmaxf(v[u], tv);
        v[u] = lo;
    }
}

__device__ __forceinline__ void compactB(float* v, const float* bp, int cnt) {
    #pragma unroll
    for (int i = 0; i < 16; ++i) {
        float tv = (i < cnt) ? bp[i] : BIGF;
        insert11(v, tv);
    }
}

__device__ __forceinline__ void ce(float& a, float& b) {
    float lo = fminf(a, b), hi = fmaxf(a, b); a = lo; b = hi;
}
// sort an 11-elem bitonic sequence ascending (clipped 16-wire bitonic merge)
__device__ __forceinline__ void sortBitonic11(float* w) {
    ce(w[0],w[8]); ce(w[1],w[9]); ce(w[2],w[10]);
    ce(w[0],w[4]); ce(w[1],w[5]); ce(w[2],w[6]); ce(w[3],w[7]);
    ce(w[0],w[2]); ce(w[1],w[3]); ce(w[4],w[6]); ce(w[5],w[7]); ce(w[8],w[10]);
    ce(w[0],w[1]); ce(w[2],w[3]); ce(w[4],w[5]); ce(w[6],w[7]); ce(w[8],w[9]);
}

// ---------------- K0: prep (s hi/lo split + weight concat/pad/split) ----------------
__global__ __launch_bounds__(256) void k_prep(
    const float* __restrict__ s,
    const float* __restrict__ w1, const float* __restrict__ wt1, const float* __restrict__ wz1,
    const float* __restrict__ w2, const float* __restrict__ wt2, const float* __restrict__ wz2,
    const float* __restrict__ w3, const float* __restrict__ wt3, const float* __restrict__ wz3,
    const float* __restrict__ b1, const float* __restrict__ bt1, const float* __restrict__ bz1,
    const float* __restrict__ b2, const float* __restrict__ bt2, const float* __restrict__ bz2,
    const float* __restrict__ b3, const float* __restrict__ bt3, const float* __restrict__ bz3,
    unsigned short* __restrict__ sh, unsigned short* __restrict__ sl,
    unsigned short* __restrict__ w1h, unsigned short* __restrict__ w1l,
    unsigned short* __restrict__ w2h, unsigned short* __restrict__ w2l,
    unsigned short* __restrict__ w3h, unsigned short* __restrict__ w3l,
    float* __restrict__ b1c, float* __restrict__ b2c, float* __restrict__ b3c)
{
    const int b = blockIdx.x;
    const int t = threadIdx.x;
    if (b < 2048) {
        size_t base = ((size_t)b * 256 + t) * 8;
        f32x4 a = *(const f32x4*)(s + base);
        f32x4 c = *(const f32x4*)(s + base + 4);
        ushort8v h, l;
        #pragma unroll
        for (int j = 0; j < 4; ++j) {
            unsigned short hh, ll;
            split_bf16(a[j], hh, ll); h[j] = hh; l[j] = ll;
            split_bf16(c[j], hh, ll); h[4 + j] = hh; l[4 + j] = ll;
        }
        *(ushort8v*)(sh + base) = h;
        *(ushort8v*)(sl + base) = l;
    } else if (b < 2240) {
        int idx = ((b - 2048) * 256 + t) * 4;
        int n = idx >> 9, k = idx & 511;
        const float* src = (n < 128) ? (w1 + (size_t)n * 512)
                         : (n < 256) ? (wt1 + (size_t)(n - 128) * 512)
                                     : (wz1 + (size_t)(n - 256) * 512);
        f32x4 v = *(const f32x4*)(src + k);
        ushort4v h, l;
        #pragma unroll
        for (int j = 0; j < 4; ++j) { unsigned short hh, ll; split_bf16(v[j], hh, ll); h[j] = hh; l[j] = ll; }
        *(ushort4v*)(w1h + idx) = h;
        *(ushort4v*)(w1l + idx) = l;
    } else if (b < 2312) {
        int idx = ((b - 2240) * 256 + t) * 4;
        int n = idx / 384, k = idx % 384;
        f32x4 v = {0.f, 0.f, 0.f, 0.f};
        if (n < 64)       { if (k < 128)             v = *(const f32x4*)(w2  + (size_t)n * 128 + k); }
        else if (n < 128) { if (k >= 128 && k < 256) v = *(const f32x4*)(wt2 + (size_t)(n - 64) * 128 + (k - 128)); }
        else              { if (k >= 256)            v = *(const f32x4*)(wz2 + (size_t)(n - 128) * 128 + (k - 256)); }
        ushort4v h, l;
        #pragma unroll
        for (int j = 0; j < 4; ++j) { unsigned short hh, ll; split_bf16(v[j], hh, ll); h[j] = hh; l[j] = ll; }
        *(ushort4v*)(w2h + idx) = h;
        *(ushort4v*)(w2l + idx) = l;
    } else if (b < 2339) {
        int idx = ((b - 2312) * 256 + t) * 4;
        int n = idx / 192, k = idx % 192;
        f32x4 v = {0.f, 0.f, 0.f, 0.f};
        if (n == 0)                 { if (k < 64)             v = *(const f32x4*)(w3 + k); }
        else if (n == 1)            { if (k >= 64 && k < 128) v = *(const f32x4*)(wt3 + (k - 64)); }
        else if (n >= 16 && n < 144){ if (k >= 128)           v = *(const f32x4*)(wz3 + (size_t)(n - 16) * 64 + (k - 128)); }
        ushort4v h, l;
        #pragma unroll
        for (int j = 0; j < 4; ++j) { unsigned short hh, ll; split_bf16(v[j], hh, ll); h[j] = hh; l[j] = ll; }
        *(ushort4v*)(w3h + idx) = h;
        *(ushort4v*)(w3l + idx) = l;
    } else {
        for (int i = t; i < 720; i += 256) {
            if (i < 384)      b1c[i] = (i < 128) ? b1[i] : (i < 256) ? bt1[i - 128] : bz1[i - 256];
            else if (i < 576) { int j = i - 384; b2c[j] = (j < 64) ? b2[j] : (j < 128) ? bt2[j - 64] : bz2[j - 128]; }
            else              { int j = i - 576; b3c[j] = (j == 0) ? b3[0] : (j == 1) ? bt3[0] : (j < 16) ? 0.f : bz3[j - 16]; }
        }
    }
}

// ---------------- GEMM1: h1 = relu(s @ W1cat^T + b1c) ----------------
// 512 blocks x 256 thr; block = 16 rows (1 m-tile), wave wv covers n-tiles wv*6..wv*6+5
__global__ __launch_bounds__(256, 4) void k_gemm1(
    const unsigned short* __restrict__ xh_, const unsigned short* __restrict__ xl_,
    const unsigned short* __restrict__ wh, const unsigned short* __restrict__ wl,
    const float* __restrict__ bias,
    unsigned short* __restrict__ outh, unsigned short* __restrict__ outl)
{
    const int t = threadIdx.x;
    const int lane = t & 63, wv = t >> 6;
    const int l15 = lane & 15, lg = lane >> 4;
    const int m = blockIdx.x * 16 + l15;
    const int nbase = wv * 6;

    f32x4 acc[6];
    #pragma unroll
    for (int i = 0; i < 6; ++i) acc[i] = (f32x4){0.f, 0.f, 0.f, 0.f};

    const unsigned short* xh = xh_ + (size_t)m * 512;
    const unsigned short* xl = xl_ + (size_t)m * 512;
    for (int kt = 0; kt < 16; ++kt) {
        const int k0 = kt * 32 + lg * 8;
        bf16x8 axh = *(const bf16x8*)(xh + k0);
        bf16x8 axl = *(const bf16x8*)(xl + k0);
        #pragma unroll
        for (int i = 0; i < 6; ++i) {
            const size_t off = (size_t)((nbase + i) * 16 + l15) * 512 + k0;
            bf16x8 bh = *(const bf16x8*)(wh + off);
            bf16x8 bl = *(const bf16x8*)(wl + off);
            acc[i] = __builtin_amdgcn_mfma_f32_16x16x32_bf16(bh, axh, acc[i], 0, 0, 0);
            acc[i] = __builtin_amdgcn_mfma_f32_16x16x32_bf16(bl, axh, acc[i], 0, 0, 0);
            acc[i] = __builtin_amdgcn_mfma_f32_16x16x32_bf16(bh, axl, acc[i], 0, 0, 0);
        }
    }
    #pragma unroll
    for (int i = 0; i < 6; ++i) {
        const int n0 = (nbase + i) * 16 + lg * 4;
        f32x4 bv = *(const f32x4*)(bias + n0);
        f32x4 v = acc[i] + bv;
        ushort4v vh, vl;
        #pragma unroll
        for (int r = 0; r < 4; ++r) {
            float x = fmaxf(v[r], 0.f);
            unsigned short hh, ll; split_bf16(x, hh, ll);
            vh[r] = hh; vl[r] = ll;
        }
        *(ushort4v*)(outh + (size_t)m * 384 + n0) = vh;
        *(ushort4v*)(outl + (size_t)m * 384 + n0) = vl;
    }
}

// ---------------- GEMM2: h2 = relu(h1 @ W2cat^T + b2c) ----------------
// 512 blocks x 256 thr; block = 16 rows, wave wv covers n-tiles wv*3..wv*3+2
__global__ __launch_bounds__(256, 4) void k_gemm2(
    const unsigned short* __restrict__ xh_, const unsigned short* __restrict__ xl_,
    const unsigned short* __restrict__ wh, const unsigned short* __restrict__ wl,
    const float* __restrict__ bias,
    unsigned short* __restrict__ outh, unsigned short* __restrict__ outl)
{
    const int t = threadIdx.x;
    const int lane = t & 63, wv = t >> 6;
    const int l15 = lane & 15, lg = lane >> 4;
    const int m = blockIdx.x * 16 + l15;
    const int nbase = wv * 3;

    f32x4 acc[3];
    #pragma unroll
    for (int i = 0; i < 3; ++i) acc[i] = (f32x4){0.f, 0.f, 0.f, 0.f};

    const unsigned short* xh = xh_ + (size_t)m * 384;
    const unsigned short* xl = xl_ + (size_t)m * 384;
    for (int kt = 0; kt < 12; ++kt) {
        const int k0 = kt * 32 + lg * 8;
        bf16x8 axh = *(const bf16x8*)(xh + k0);
        bf16x8 axl = *(const bf16x8*)(xl + k0);
        #pragma unroll
        for (int i = 0; i < 3; ++i) {
            const size_t off = (size_t)((nbase + i) * 16 + l15) * 384 + k0;
            bf16x8 bh = *(const bf16x8*)(wh + off);
            bf16x8 bl = *(const bf16x8*)(wl + off);
            acc[i] = __builtin_amdgcn_mfma_f32_16x16x32_bf16(bh, axh, acc[i], 0, 0, 0);
            acc[i] = __builtin_amdgcn_mfma_f32_16x16x32_bf16(bl, axh, acc[i], 0, 0, 0);
            acc[i] = __builtin_amdgcn_mfma_f32_16x16x32_bf16(bh, axl, acc[i], 0, 0, 0);
        }
    }
    #pragma unroll
    for (int i = 0; i < 3; ++i) {
        const int n0 = (nbase + i) * 16 + lg * 4;
        f32x4 bv = *(const f32x4*)(bias + n0);
        f32x4 v = acc[i] + bv;
        ushort4v vh, vl;
        #pragma unroll
        for (int r = 0; r < 4; ++r) {
            float x = fmaxf(v[r], 0.f);
            unsigned short hh, ll; split_bf16(x, hh, ll);
            vh[r] = hh; vl[r] = ll;
        }
        *(ushort4v*)(outh + (size_t)m * 192 + n0) = vh;
        *(ushort4v*)(outl + (size_t)m * 192 + n0) = vl;
    }
}

// ---------------- GEMM3: out144 = h2 @ W3cat^T + b3c; epilogue -> zb/sq/alpha ----------------
// 512 blocks x 256 thr; block = 16 rows; wave wv: nb = wv?2wv+1:0, nc = wv?2:3
__global__ __launch_bounds__(256, 4) void k_gemm3(
    const unsigned short* __restrict__ xh_, const unsigned short* __restrict__ xl_,
    const unsigned short* __restrict__ wh, const unsigned short* __restrict__ wl,
    const float* __restrict__ bias,
    unsigned short* __restrict__ zb, float* __restrict__ sq, float* __restrict__ alpha)
{
    __shared__ float sred[4][16];
    const int t = threadIdx.x;
    const int lane = t & 63, wv = t >> 6;
    const int l15 = lane & 15, lg = lane >> 4;
    const int m = blockIdx.x * 16 + l15;
    const int nb = wv ? (2 * wv + 1) : 0;
    const int nc = wv ? 2 : 3;

    f32x4 acc[3];
    #pragma unroll
    for (int i = 0; i < 3; ++i) acc[i] = (f32x4){0.f, 0.f, 0.f, 0.f};

    const unsigned short* xh = xh_ + (size_t)m * 192;
    const unsigned short* xl = xl_ + (size_t)m * 192;
    for (int kt = 0; kt < 6; ++kt) {
        const int k0 = kt * 32 + lg * 8;
        bf16x8 axh = *(const bf16x8*)(xh + k0);
        bf16x8 axl = *(const bf16x8*)(xl + k0);
        #pragma unroll
        for (int i = 0; i < 3; ++i) {
            if (i < nc) {
                const size_t off = (size_t)((nb + i) * 16 + l15) * 192 + k0;
                bf16x8 bh = *(const bf16x8*)(wh + off);
                bf16x8 bl = *(const bf16x8*)(wl + off);
                acc[i] = __builtin_amdgcn_mfma_f32_16x16x32_bf16(bh, axh, acc[i], 0, 0, 0);
                acc[i] = __builtin_amdgcn_mfma_f32_16x16x32_bf16(bl, axh, acc[i], 0, 0, 0);
                acc[i] = __builtin_amdgcn_mfma_f32_16x16x32_bf16(bh, axl, acc[i], 0, 0, 0);
            }
        }
    }

    float ssq = 0.f;
    float pred = 0.f, tgt = 0.f;
    #pragma unroll
    for (int i = 0; i < 3; ++i) {
        if (i < nc) {
            const int ntg = nb + i;
            const int n0 = ntg * 16 + lg * 4;
            f32x4 bv = *(const f32x4*)(bias + n0);
            f32x4 v = acc[i] + bv;
            if (ntg == 0) {
                if (lg == 0) { pred = v.x; tgt = v.y; }
            } else {
                ushort4v zu;
                #pragma unroll
                for (int r = 0; r < 4; ++r) {
                    unsigned short us = f32_to_bf16_rne(v[r]);
                    float zf = __uint_as_float(((unsigned int)us) << 16);
                    ssq += zf * zf;
                    zu[r] = us;
                }
                *(ushort4v*)(zb + (size_t)m * FDIM + (ntg - 1) * 16 + lg * 4) = zu;
            }
        }
    }
    ssq += __shfl_xor(ssq, 16);
    ssq += __shfl_xor(ssq, 32);
    if (lg == 0) sred[wv][l15] = ssq;
    __syncthreads();
    if (t < 16) {
        sq[blockIdx.x * 16 + t] = sred[0][t] + sred[1][t] + sred[2][t] + sred[3][t];
    }
    if (wv == 0 && lg == 0) {
        float d = pred - tgt;
        alpha[m] = d * d;
    }
}

// ---------------- K2: pairwise + threshold-filtered top-11 ----------------
// 1024 blocks x 256 thr; split = b&15 (shared by 4 waves -> L1 reuse),
// qg = (b>>4)*4 + wave. Wave: 32 queries x 512 candidates (32 tiles).
// Self-pair key (-sq_q) is the provable min -> dropped in k_merge.
__global__ __launch_bounds__(256, 4) void k_pairs(
    const unsigned short* __restrict__ zb, const float* __restrict__ sq,
    float* __restrict__ part)
{
    __shared__ float buf[4][2][64][BCAP];   // 34816 B
    __shared__ float sqs[512];
    const int t = threadIdx.x;
    const int lane = t & 63;
    const int wv = t >> 6;
    const int split = blockIdx.x & 15;
    const int qg = (blockIdx.x >> 4) * 4 + wv;
    const int l15 = lane & 15, lg = lane >> 4;
    const int c0 = split * 512;

    sqs[t] = sq[c0 + t];
    sqs[t + 256] = sq[c0 + t + 256];
    __syncthreads();

    float* bp0 = &buf[wv][0][lane][0];
    float* bp1 = &buf[wv][1][lane][0];

    const int qid0 = qg * 32 + l15;
    const int qid1 = qg * 32 + 16 + l15;
    bf16x8 bq[2][4];
    #pragma unroll
    for (int kk = 0; kk < 4; ++kk) {
        bq[0][kk] = *(const bf16x8*)(zb + (size_t)qid0 * FDIM + kk * 32 + lg * 8);
        bq[1][kk] = *(const bf16x8*)(zb + (size_t)qid1 * FDIM + kk * 32 + lg * 8);
    }

    float vals[2][K2];
    #pragma unroll
    for (int qt = 0; qt < 2; ++qt)
        #pragma unroll
        for (int i = 0; i < K2; ++i) vals[qt][i] = BIGF;
    float thr0 = BIGF, thr1 = BIGF;
    int cnt0 = 0, cnt1 = 0;

    bf16x8 av[4];
    {
        const unsigned short* zp = zb + (size_t)(c0 + l15) * FDIM + lg * 8;
        #pragma unroll
        for (int kk = 0; kk < 4; ++kk) av[kk] = *(const bf16x8*)(zp + kk * 32);
    }

    for (int tile = 0; tile < 32; ++tile) {
        f32x4 acc0 = {0.f, 0.f, 0.f, 0.f};
        f32x4 acc1 = {0.f, 0.f, 0.f, 0.f};
        #pragma unroll
        for (int kk = 0; kk < 4; ++kk) {
            acc0 = __builtin_amdgcn_mfma_f32_16x16x32_bf16(av[kk], bq[0][kk], acc0, 0, 0, 0);
            acc1 = __builtin_amdgcn_mfma_f32_16x16x32_bf16(av[kk], bq[1][kk], acc1, 0, 0, 0);
        }
        if (tile < 31) {
            const unsigned short* zp = zb + (size_t)(c0 + (tile + 1) * 16 + l15) * FDIM + lg * 8;
            #pragma unroll
            for (int kk = 0; kk < 4; ++kk) av[kk] = *(const bf16x8*)(zp + kk * 32);
        }
        f32x4 sqv = *(const f32x4*)(&sqs[tile * 16 + lg * 4]);
        #pragma unroll
        for (int r = 0; r < 4; ++r) {
            float v0 = fmaf(-2.0f, acc0[r], sqv[r]);     // key = dist^2 - sq_q
            bp0[cnt0] = v0;
            cnt0 += (int)(v0 < thr0);
            float v1 = fmaf(-2.0f, acc1[r], sqv[r]);
            bp1[cnt1] = v1;
            cnt1 += (int)(v1 < thr1);
        }
        if (__any(cnt0 >= TRIG)) { compactB(vals[0], bp0, cnt0); thr0 = vals[0][K2 - 1]; cnt0 = 0; }
        if (__any(cnt1 >= TRIG)) { compactB(vals[1], bp1, cnt1); thr1 = vals[1][K2 - 1]; cnt1 = 0; }
    }
    compactB(vals[0], bp0, cnt0);
    compactB(vals[1], bp1, cnt1);

    // cross-lane-group merge: ^16 min-trick -> bitonic sort -> ^32 min-trick
    #pragma unroll
    for (int qt = 0; qt < 2; ++qt) {
        float wk[K2];
        #pragma unroll
        for (int i = 0; i < K2; ++i) {
            float o = __shfl_xor(vals[qt][K2 - 1 - i], 16);
            wk[i] = fminf(vals[qt][i], o);
        }
        sortBitonic11(wk);
        float m1[K2];
        #pragma unroll
        for (int i = 0; i < K2; ++i) {
            float o = __shfl_xor(wk[K2 - 1 - i], 32);
            m1[i] = fminf(wk[i], o);
        }
        if (lg == 0) {
            const int qid = (qt == 0) ? qid0 : qid1;
            float* dst = part + ((size_t)split * NROWS + qid) * K2;
            #pragma unroll
            for (int i = 0; i < K2; ++i) dst[i] = m1[i];
        }
    }
}

// ---------------- K3: merge 16 partial 11-lists (2 threads/q); drop min (self) ----------------
__global__ __launch_bounds__(256) void k_merge(
    const float* __restrict__ part, const float* __restrict__ sq,
    float* __restrict__ sumk, float* __restrict__ total)
{
    __shared__ float xb[128][K2 + 1];
    __shared__ float red[4];
    const int t = threadIdx.x;
    const int qi = t & 127, hf = t >> 7;
    const int q = blockIdx.x * 128 + qi;

    float vals[K2];
    #pragma unroll
    for (int i = 0; i < K2; ++i) vals[i] = BIGF;
    for (int seg = hf * 8; seg < hf * 8 + 8; ++seg) {
        const float* p = part + ((size_t)seg * NROWS + q) * K2;
        #pragma unroll
        for (int i = 0; i < K2; ++i) {
            float tv = p[i];
            if (tv < vals[K2 - 1]) insert11(vals, tv);
        }
    }
    if (hf) {
        #pragma unroll
        for (int i = 0; i < K2; ++i) xb[qi][i] = vals[i];
    }
    __syncthreads();
    float sum = 0.f;
    if (!hf) {
        #pragma unroll
        for (int i = 0; i < K2; ++i) {
            float tv = xb[qi][i];
            if (tv < vals[K2 - 1]) insert11(vals, tv);
        }
        float sqq = sq[q];
        #pragma unroll
        for (int i = 1; i < K2; ++i) {          // skip vals[0] = self
            float raw = sqq + vals[i];
            sum += (raw > 0.f) ? sqrtf(raw) : 0.f;
        }
        sumk[q] = sum;
    }
    #pragma unroll
    for (int off = 32; off > 0; off >>= 1) sum += __shfl_down(sum, off);
    if ((t & 63) == 0) red[t >> 6] = sum;
    __syncthreads();
    if (t == 0) atomicAdd(total, red[0] + red[1] + red[2] + red[3]);
}

// ---------------- K4: finalize ----------------
__global__ __launch_bounds__(256) void k_final(
    const float* __restrict__ sumk, const float* __restrict__ alpha,
    const float* __restrict__ total, float* __restrict__ out)
{
    const int q = blockIdx.x * 256 + threadIdx.x;
    float mean = (*total) * (1.0f / NROWS);
    float m2 = mean * mean;
    float sk = sumk[q];
    float x = (sk * sk) / m2;
    float knn = EPS_CONST / (x + EPS_CONST);
    float rep = 1.0f / (sqrtf(knn) + C_CONST);
    float a = alpha[q];
    a = fminf(fmaxf(a, 1.0f), L_CONST);
    out[q] = rep * a;
}

extern "C" void kernel_launch(void* const* d_in, const int* in_sizes, int n_in,
                              void* d_out, int out_size, void* d_ws, size_t ws_size,
                              hipStream_t stream) {
    const float* s   = (const float*)d_in[0];
    const float* w1  = (const float*)d_in[1];
    const float* b1  = (const float*)d_in[2];
    const float* w2  = (const float*)d_in[3];
    const float* b2  = (const float*)d_in[4];
    const float* w3  = (const float*)d_in[5];
    const float* b3  = (const float*)d_in[6];
    const float* wt1 = (const float*)d_in[7];
    const float* bt1 = (const float*)d_in[8];
    const float* wt2 = (const float*)d_in[9];
    const float* bt2 = (const float*)d_in[10];
    const float* wt3 = (const float*)d_in[11];
    const float* bt3 = (const float*)d_in[12];
    const float* wz1 = (const float*)d_in[13];
    const float* bz1 = (const float*)d_in[14];
    const float* wz2 = (const float*)d_in[15];
    const float* bz2 = (const float*)d_in[16];
    const float* wz3 = (const float*)d_in[17];
    const float* bz3 = (const float*)d_in[18];

    char* ws = (char*)d_ws;
    unsigned short* zb  = (unsigned short*)(ws);                // 2097152
    float* sq    = (float*)(ws + 2097152);                      // 32768
    float* alpha = (float*)(ws + 2129920);                      // 32768
    float* part  = (float*)(ws + 2162688);                      // 16*8192*11*4 = 5767168
    float* sumk  = (float*)(ws + 7929856);                      // 32768
    float* total = (float*)(ws + 7962624);                      // 256
    unsigned short* h1h = (unsigned short*)(ws + 7962880);      // 6291456
    unsigned short* h1l = (unsigned short*)(ws + 14254336);     // 6291456
    unsigned short* h2h = (unsigned short*)(ws + 20545792);     // 3145728
    unsigned short* h2l = (unsigned short*)(ws + 23691520);     // 3145728
    unsigned short* sh  = (unsigned short*)(ws + 26837248);     // 8388608
    unsigned short* sl  = (unsigned short*)(ws + 35225856);     // 8388608
    unsigned short* w1h = (unsigned short*)(ws + 43614464);     // 393216
    unsigned short* w1l = (unsigned short*)(ws + 44007680);     // 393216
    unsigned short* w2h = (unsigned short*)(ws + 44400896);     // 147456
    unsigned short* w2l = (unsigned short*)(ws + 44548352);     // 147456
    unsigned short* w3h = (unsigned short*)(ws + 44695808);     // 55296
    unsigned short* w3l = (unsigned short*)(ws + 44751104);     // 55296
    float* b1c = (float*)(ws + 44806400);
    float* b2c = (float*)(ws + 44807936);
    float* b3c = (float*)(ws + 44808704);

    hipMemsetAsync(total, 0, sizeof(float), stream);

    k_prep<<<2340, 256, 0, stream>>>(s,
                                     w1, wt1, wz1, w2, wt2, wz2, w3, wt3, wz3,
                                     b1, bt1, bz1, b2, bt2, bz2, b3, bt3, bz3,
                                     sh, sl, w1h, w1l, w2h, w2l, w3h, w3l, b1c, b2c, b3c);
    k_gemm1<<<512, 256, 0, stream>>>(sh, sl, w1h, w1l, b1c, h1h, h1l);
    k_gemm2<<<512, 256, 0, stream>>>(h1h, h1l, w2h, w2l, b2c, h2h, h2l);
    k_gemm3<<<512, 256, 0, stream>>>(h2h, h2l, w3h, w3l, b3c, zb, sq, alpha);
    k_pairs<<<1024, 256, 0, stream>>>(zb, sq, part);
    k_merge<<<64, 256, 0, stream>>>(part, sq, sumk, total);
    k_final<<<32, 256, 0, stream>>>(sumk, alpha, total, (float*)d_out);
}

// Round 7
// 144.160 us; speedup vs baseline: 2.1198x; 1.3833x over previous
//
#include <hip/hip_runtime.h>
#include <hip/hip_bf16.h>

#define NROWS 8192
#define FDIM 128
#define KNN 10
#define K2 11
#define C_CONST 1.0e-3f
#define L_CONST 5.0f
#define EPS_CONST 1.0e-3f
#define BIGF 3.0e38f
#define BCAP 17
#define TRIG 13
#define NSEG 16

typedef float f32x4 __attribute__((ext_vector_type(4)));
typedef __bf16 bf16x8 __attribute__((ext_vector_type(8)));
typedef unsigned short ushort4v __attribute__((ext_vector_type(4)));
typedef unsigned short ushort8v __attribute__((ext_vector_type(8)));

__device__ __forceinline__ unsigned short f32_to_bf16_rne(float f) {
    unsigned int x = __float_as_uint(f);
    unsigned int lsb = (x >> 16) & 1u;
    x += 0x7fffu + lsb;
    return (unsigned short)(x >> 16);
}

__device__ __forceinline__ void split_bf16(float v, unsigned short& h, unsigned short& l) {
    unsigned short hh = f32_to_bf16_rne(v);
    float hf = __uint_as_float(((unsigned int)hh) << 16);
    h = hh;
    l = f32_to_bf16_rne(v - hf);
}

__device__ __forceinline__ void insert11(float* v, float tv) {
    #pragma unroll
    for (int u = 0; u < K2; ++u) {
        float lo = fminf(v[u], tv);
        tv = fmaxf(v[u], tv);
        v[u] = lo;
    }
}

__device__ __forceinline__ void compactB(float* v, const float* bp, int cnt) {
    #pragma unroll
    for (int i = 0; i < 16; ++i) {
        float tv = (i < cnt) ? bp[i] : BIGF;
        insert11(v, tv);
    }
}

__device__ __forceinline__ void ce(float& a, float& b) {
    float lo = fminf(a, b), hi = fmaxf(a, b); a = lo; b = hi;
}
__device__ __forceinline__ void sortBitonic11(float* w) {
    ce(w[0],w[8]); ce(w[1],w[9]); ce(w[2],w[10]);
    ce(w[0],w[4]); ce(w[1],w[5]); ce(w[2],w[6]); ce(w[3],w[7]);
    ce(w[0],w[2]); ce(w[1],w[3]); ce(w[4],w[6]); ce(w[5],w[7]); ce(w[8],w[10]);
    ce(w[0],w[1]); ce(w[2],w[3]); ce(w[4],w[5]); ce(w[6],w[7]); ce(w[8],w[9]);
}

// ---------------- K0: prep — build ALL tensors in fragment-major layout ----------------
// layout: frag[tile][kt][lane][2][8] (hi 8 shorts, lo 8 shorts), lane=(k>>3&3)*16+(row&15)
__global__ __launch_bounds__(256) void k_prep(
    const float* __restrict__ s,
    const float* __restrict__ w1, const float* __restrict__ wt1, const float* __restrict__ wz1,
    const float* __restrict__ w2, const float* __restrict__ wt2, const float* __restrict__ wz2,
    const float* __restrict__ w3, const float* __restrict__ wt3, const float* __restrict__ wz3,
    const float* __restrict__ b1, const float* __restrict__ bt1, const float* __restrict__ bz1,
    const float* __restrict__ b2, const float* __restrict__ bt2, const float* __restrict__ bz2,
    const float* __restrict__ b3, const float* __restrict__ bt3, const float* __restrict__ bz3,
    unsigned short* __restrict__ sf,
    unsigned short* __restrict__ w1f, unsigned short* __restrict__ w2f,
    unsigned short* __restrict__ w3f,
    float* __restrict__ b1c, float* __restrict__ b2c, float* __restrict__ b3c)
{
    const int b = blockIdx.x;
    const int t = threadIdx.x;
    const int wv = t >> 6, lane = t & 63;
    const int l15 = lane & 15, lg = lane >> 4;

    if (b < 2048) {
        // s fragments: 8192 waves, wave=(mt,kt); mt in [0,512), kt in [0,16)
        const int w = b * 4 + wv;
        const int mt = w >> 4, kt = w & 15;
        const float* src = s + (size_t)(mt * 16 + l15) * 512 + kt * 32 + lg * 8;
        f32x4 a = *(const f32x4*)src;
        f32x4 c = *(const f32x4*)(src + 4);
        ushort8v h, l;
        #pragma unroll
        for (int j = 0; j < 4; ++j) {
            unsigned short hh, ll;
            split_bf16(a[j], hh, ll); h[j] = hh; l[j] = ll;
            split_bf16(c[j], hh, ll); h[4 + j] = hh; l[4 + j] = ll;
        }
        unsigned short* dst = sf + ((size_t)(mt * 16 + kt) * 64 + lane) * 16;
        *(ushort8v*)dst = h;
        *(ushort8v*)(dst + 8) = l;
    } else if (b < 2144) {
        // W1cat [384][512]: 384 waves (nt 0..23, kt 0..15)
        const int w = (b - 2048) * 4 + wv;
        const int nt = w >> 4, kt = w & 15;
        const int n = nt * 16 + l15, k = kt * 32 + lg * 8;
        const float* src = (n < 128) ? (w1 + (size_t)n * 512 + k)
                         : (n < 256) ? (wt1 + (size_t)(n - 128) * 512 + k)
                                     : (wz1 + (size_t)(n - 256) * 512 + k);
        f32x4 a = *(const f32x4*)src;
        f32x4 c = *(const f32x4*)(src + 4);
        ushort8v h, l;
        #pragma unroll
        for (int j = 0; j < 4; ++j) {
            unsigned short hh, ll;
            split_bf16(a[j], hh, ll); h[j] = hh; l[j] = ll;
            split_bf16(c[j], hh, ll); h[4 + j] = hh; l[4 + j] = ll;
        }
        unsigned short* dst = w1f + ((size_t)(nt * 16 + kt) * 64 + lane) * 16;
        *(ushort8v*)dst = h;
        *(ushort8v*)(dst + 8) = l;
    } else if (b < 2180) {
        // W2cat [192][384] block-diag: 144 waves (nt 0..11, kt 0..11)
        const int w = (b - 2144) * 4 + wv;
        const int nt = w / 12, kt = w % 12;
        const int n = nt * 16 + l15, k = kt * 32 + lg * 8;
        f32x4 a = {0.f,0.f,0.f,0.f}, c = {0.f,0.f,0.f,0.f};
        if (n < 64)       { if (k < 128)             { const float* p = w2  + (size_t)n * 128 + k;            a = *(const f32x4*)p; c = *(const f32x4*)(p + 4); } }
        else if (n < 128) { if (k >= 128 && k < 256) { const float* p = wt2 + (size_t)(n - 64) * 128 + (k - 128);  a = *(const f32x4*)p; c = *(const f32x4*)(p + 4); } }
        else              { if (k >= 256)            { const float* p = wz2 + (size_t)(n - 128) * 128 + (k - 256); a = *(const f32x4*)p; c = *(const f32x4*)(p + 4); } }
        ushort8v h, l;
        #pragma unroll
        for (int j = 0; j < 4; ++j) {
            unsigned short hh, ll;
            split_bf16(a[j], hh, ll); h[j] = hh; l[j] = ll;
            split_bf16(c[j], hh, ll); h[4 + j] = hh; l[4 + j] = ll;
        }
        unsigned short* dst = w2f + ((size_t)(nt * 12 + kt) * 64 + lane) * 16;
        *(ushort8v*)dst = h;
        *(ushort8v*)(dst + 8) = l;
    } else if (b < 2194) {
        // W3cat [144][192]: 54 waves (nt 0..8, kt 0..5)
        const int w = (b - 2180) * 4 + wv;
        if (w < 54) {
            const int nt = w / 6, kt = w % 6;
            const int n = nt * 16 + l15, k = kt * 32 + lg * 8;
            f32x4 a = {0.f,0.f,0.f,0.f}, c = {0.f,0.f,0.f,0.f};
            if (n == 0)                  { if (k < 64)             { const float* p = w3 + k;                        a = *(const f32x4*)p; c = *(const f32x4*)(p + 4); } }
            else if (n == 1)             { if (k >= 64 && k < 128) { const float* p = wt3 + (k - 64);               a = *(const f32x4*)p; c = *(const f32x4*)(p + 4); } }
            else if (n >= 16 && n < 144) { if (k >= 128)           { const float* p = wz3 + (size_t)(n - 16) * 64 + (k - 128); a = *(const f32x4*)p; c = *(const f32x4*)(p + 4); } }
            ushort8v h, l;
            #pragma unroll
            for (int j = 0; j < 4; ++j) {
                unsigned short hh, ll;
                split_bf16(a[j], hh, ll); h[j] = hh; l[j] = ll;
                split_bf16(c[j], hh, ll); h[4 + j] = hh; l[4 + j] = ll;
            }
            unsigned short* dst = w3f + ((size_t)(nt * 6 + kt) * 64 + lane) * 16;
            *(ushort8v*)dst = h;
            *(ushort8v*)(dst + 8) = l;
        }
    } else {
        for (int i = t; i < 720; i += 256) {
            if (i < 384)      b1c[i] = (i < 128) ? b1[i] : (i < 256) ? bt1[i - 128] : bz1[i - 256];
            else if (i < 576) { int j = i - 384; b2c[j] = (j < 64) ? b2[j] : (j < 128) ? bt2[j - 64] : bz2[j - 128]; }
            else              { int j = i - 576; b3c[j] = (j == 0) ? b3[0] : (j == 1) ? bt3[0] : (j < 16) ? 0.f : bz3[j - 16]; }
        }
    }
}

// ---------------- GEMM1: h1 = relu(s @ W1cat^T + b1c), fragment-major I/O ----------------
// 512 blocks x 256 thr; block = m-tile (16 rows); wave wv -> n-tiles wv*6..+5
__global__ __launch_bounds__(256, 4) void k_gemm1(
    const unsigned short* __restrict__ sf, const unsigned short* __restrict__ w1f,
    const float* __restrict__ bias, unsigned short* __restrict__ h1f)
{
    const int t = threadIdx.x;
    const int lane = t & 63, wv = t >> 6;
    const int l15 = lane & 15, lg = lane >> 4;
    const int mt = blockIdx.x;

    f32x4 acc[6];
    #pragma unroll
    for (int i = 0; i < 6; ++i) acc[i] = (f32x4){0.f, 0.f, 0.f, 0.f};

    for (int kt = 0; kt < 16; ++kt) {
        const unsigned short* ap = sf + ((size_t)(mt * 16 + kt) * 64 + lane) * 16;
        bf16x8 axh = *(const bf16x8*)ap;
        bf16x8 axl = *(const bf16x8*)(ap + 8);
        #pragma unroll
        for (int i = 0; i < 6; ++i) {
            const unsigned short* wp = w1f + ((size_t)((wv * 6 + i) * 16 + kt) * 64 + lane) * 16;
            bf16x8 bh = *(const bf16x8*)wp;
            bf16x8 bl = *(const bf16x8*)(wp + 8);
            acc[i] = __builtin_amdgcn_mfma_f32_16x16x32_bf16(bh, axh, acc[i], 0, 0, 0);
            acc[i] = __builtin_amdgcn_mfma_f32_16x16x32_bf16(bl, axh, acc[i], 0, 0, 0);
            acc[i] = __builtin_amdgcn_mfma_f32_16x16x32_bf16(bh, axl, acc[i], 0, 0, 0);
        }
    }
    #pragma unroll
    for (int i = 0; i < 6; ++i) {
        const int ntile = wv * 6 + i;
        const int n0 = ntile * 16 + lg * 4;
        f32x4 bv = *(const f32x4*)(bias + n0);
        f32x4 v = acc[i] + bv;
        ushort4v vh, vl;
        #pragma unroll
        for (int r = 0; r < 4; ++r) {
            float x = fmaxf(v[r], 0.f);
            unsigned short hh, ll; split_bf16(x, hh, ll);
            vh[r] = hh; vl[r] = ll;
        }
        const int ch = ntile * 2 + (lg >> 1);
        const int kt2 = ch >> 2;
        const int lane2 = (ch & 3) * 16 + l15;
        const int e0 = (lg & 1) * 4;
        unsigned short* dst = h1f + ((size_t)(mt * 12 + kt2) * 64 + lane2) * 16 + e0;
        *(ushort4v*)dst = vh;
        *(ushort4v*)(dst + 8) = vl;
    }
}

// ---------------- GEMM2: h2 = relu(h1 @ W2cat^T + b2c) ----------------
// 512 blocks x 256 thr; wave wv -> n-tiles wv*3..+2 (N=192)
__global__ __launch_bounds__(256, 4) void k_gemm2(
    const unsigned short* __restrict__ h1f, const unsigned short* __restrict__ w2f,
    const float* __restrict__ bias, unsigned short* __restrict__ h2f)
{
    const int t = threadIdx.x;
    const int lane = t & 63, wv = t >> 6;
    const int l15 = lane & 15, lg = lane >> 4;
    const int mt = blockIdx.x;

    f32x4 acc[3];
    #pragma unroll
    for (int i = 0; i < 3; ++i) acc[i] = (f32x4){0.f, 0.f, 0.f, 0.f};

    for (int kt = 0; kt < 12; ++kt) {
        const unsigned short* ap = h1f + ((size_t)(mt * 12 + kt) * 64 + lane) * 16;
        bf16x8 axh = *(const bf16x8*)ap;
        bf16x8 axl = *(const bf16x8*)(ap + 8);
        #pragma unroll
        for (int i = 0; i < 3; ++i) {
            const unsigned short* wp = w2f + ((size_t)((wv * 3 + i) * 12 + kt) * 64 + lane) * 16;
            bf16x8 bh = *(const bf16x8*)wp;
            bf16x8 bl = *(const bf16x8*)(wp + 8);
            acc[i] = __builtin_amdgcn_mfma_f32_16x16x32_bf16(bh, axh, acc[i], 0, 0, 0);
            acc[i] = __builtin_amdgcn_mfma_f32_16x16x32_bf16(bl, axh, acc[i], 0, 0, 0);
            acc[i] = __builtin_amdgcn_mfma_f32_16x16x32_bf16(bh, axl, acc[i], 0, 0, 0);
        }
    }
    #pragma unroll
    for (int i = 0; i < 3; ++i) {
        const int ntile = wv * 3 + i;
        const int n0 = ntile * 16 + lg * 4;
        f32x4 bv = *(const f32x4*)(bias + n0);
        f32x4 v = acc[i] + bv;
        ushort4v vh, vl;
        #pragma unroll
        for (int r = 0; r < 4; ++r) {
            float x = fmaxf(v[r], 0.f);
            unsigned short hh, ll; split_bf16(x, hh, ll);
            vh[r] = hh; vl[r] = ll;
        }
        const int ch = ntile * 2 + (lg >> 1);
        const int kt2 = ch >> 2;
        const int lane2 = (ch & 3) * 16 + l15;
        const int e0 = (lg & 1) * 4;
        unsigned short* dst = h2f + ((size_t)(mt * 6 + kt2) * 64 + lane2) * 16 + e0;
        *(ushort4v*)dst = vh;
        *(ushort4v*)(dst + 8) = vl;
    }
}

// ---------------- GEMM3: out144 = h2 @ W3cat^T + b3c -> zf (fragment-major) / sq / alpha ----------------
__global__ __launch_bounds__(256, 4) void k_gemm3(
    const unsigned short* __restrict__ h2f, const unsigned short* __restrict__ w3f,
    const float* __restrict__ bias,
    unsigned short* __restrict__ zf, float* __restrict__ sq, float* __restrict__ alpha)
{
    __shared__ float sred[4][16];
    const int t = threadIdx.x;
    const int lane = t & 63, wv = t >> 6;
    const int l15 = lane & 15, lg = lane >> 4;
    const int mt = blockIdx.x;
    const int nb = wv ? (2 * wv + 1) : 0;   // 0,3,5,7
    const int nc = wv ? 2 : 3;

    f32x4 acc[3];
    #pragma unroll
    for (int i = 0; i < 3; ++i) acc[i] = (f32x4){0.f, 0.f, 0.f, 0.f};

    for (int kt = 0; kt < 6; ++kt) {
        const unsigned short* ap = h2f + ((size_t)(mt * 6 + kt) * 64 + lane) * 16;
        bf16x8 axh = *(const bf16x8*)ap;
        bf16x8 axl = *(const bf16x8*)(ap + 8);
        #pragma unroll
        for (int i = 0; i < 3; ++i) {
            if (i < nc) {
                const unsigned short* wp = w3f + ((size_t)((nb + i) * 6 + kt) * 64 + lane) * 16;
                bf16x8 bh = *(const bf16x8*)wp;
                bf16x8 bl = *(const bf16x8*)(wp + 8);
                acc[i] = __builtin_amdgcn_mfma_f32_16x16x32_bf16(bh, axh, acc[i], 0, 0, 0);
                acc[i] = __builtin_amdgcn_mfma_f32_16x16x32_bf16(bl, axh, acc[i], 0, 0, 0);
                acc[i] = __builtin_amdgcn_mfma_f32_16x16x32_bf16(bh, axl, acc[i], 0, 0, 0);
            }
        }
    }

    float ssq = 0.f;
    float pred = 0.f, tgt = 0.f;
    #pragma unroll
    for (int i = 0; i < 3; ++i) {
        if (i < nc) {
            const int ntg = nb + i;
            const int n0 = ntg * 16 + lg * 4;
            f32x4 bv = *(const f32x4*)(bias + n0);
            f32x4 v = acc[i] + bv;
            if (ntg == 0) {
                if (lg == 0) { pred = v.x; tgt = v.y; }
            } else {
                ushort4v zu;
                #pragma unroll
                for (int r = 0; r < 4; ++r) {
                    unsigned short us = f32_to_bf16_rne(v[r]);
                    float zf32 = __uint_as_float(((unsigned int)us) << 16);
                    ssq += zf32 * zf32;
                    zu[r] = us;
                }
                const int ch = (ntg - 1) * 2 + (lg >> 1);
                const int kk = ch >> 2;
                const int lane2 = (ch & 3) * 16 + l15;
                const int e0 = (lg & 1) * 4;
                *(ushort4v*)(zf + ((size_t)(mt * 4 + kk) * 64 + lane2) * 8 + e0) = zu;
            }
        }
    }
    ssq += __shfl_xor(ssq, 16);
    ssq += __shfl_xor(ssq, 32);
    if (lg == 0) sred[wv][l15] = ssq;
    __syncthreads();
    if (t < 16) {
        sq[blockIdx.x * 16 + t] = sred[0][t] + sred[1][t] + sred[2][t] + sred[3][t];
    }
    if (wv == 0 && lg == 0) {
        float d = pred - tgt;
        alpha[mt * 16 + l15] = d * d;
    }
}

// ---------------- K2: pairwise + threshold-filtered top-11, fragment-major zf ----------------
// 1024 blocks x 256 thr; split = b&15, qg = (b>>4)*4 + wave; 32 queries x 512 cands.
// Self-pair key (-sq_q) is the provable min -> dropped in k_merge.
__global__ __launch_bounds__(256, 4) void k_pairs(
    const unsigned short* __restrict__ zf, const float* __restrict__ sq,
    float* __restrict__ part)
{
    __shared__ float buf[4][2][64][BCAP];   // 34816 B
    __shared__ float sqs[512];
    const int t = threadIdx.x;
    const int lane = t & 63;
    const int wv = t >> 6;
    const int split = blockIdx.x & 15;
    const int qg = (blockIdx.x >> 4) * 4 + wv;
    const int l15 = lane & 15, lg = lane >> 4;
    const int c0 = split * 512;

    sqs[t] = sq[c0 + t];
    sqs[t + 256] = sq[c0 + t + 256];
    __syncthreads();

    float* bp0 = &buf[wv][0][lane][0];
    float* bp1 = &buf[wv][1][lane][0];

    const int qid0 = qg * 32 + l15;
    const int qid1 = qg * 32 + 16 + l15;
    // query fragments: tiles qg*2, qg*2+1
    bf16x8 bq[2][4];
    {
        const unsigned short* qp0 = zf + ((size_t)(qg * 2) * 256 + lane) * 8;
        const unsigned short* qp1 = zf + ((size_t)(qg * 2 + 1) * 256 + lane) * 8;
        #pragma unroll
        for (int kk = 0; kk < 4; ++kk) {
            bq[0][kk] = *(const bf16x8*)(qp0 + kk * 512);
            bq[1][kk] = *(const bf16x8*)(qp1 + kk * 512);
        }
    }

    float vals[2][K2];
    #pragma unroll
    for (int qt = 0; qt < 2; ++qt)
        #pragma unroll
        for (int i = 0; i < K2; ++i) vals[qt][i] = BIGF;
    float thr0 = BIGF, thr1 = BIGF;
    int cnt0 = 0, cnt1 = 0;

    // candidate fragments: tile stride 2048 shorts
    const unsigned short* zcl = zf + ((size_t)(split * 32) * 256 + lane) * 8;
    bf16x8 avA[4], avB[4];
    #pragma unroll
    for (int kk = 0; kk < 4; ++kk) avA[kk] = *(const bf16x8*)(zcl + kk * 512);
    #pragma unroll
    for (int kk = 0; kk < 4; ++kk) avB[kk] = *(const bf16x8*)(zcl + 2048 + kk * 512);

    for (int tile = 0; tile < 32; tile += 2) {
        // ---- even tile (avA) ----
        {
            f32x4 acc0 = {0.f,0.f,0.f,0.f}, acc1 = {0.f,0.f,0.f,0.f};
            #pragma unroll
            for (int kk = 0; kk < 4; ++kk) {
                acc0 = __builtin_amdgcn_mfma_f32_16x16x32_bf16(avA[kk], bq[0][kk], acc0, 0, 0, 0);
                acc1 = __builtin_amdgcn_mfma_f32_16x16x32_bf16(avA[kk], bq[1][kk], acc1, 0, 0, 0);
            }
            if (tile + 2 < 32) {
                const unsigned short* p = zcl + (size_t)(tile + 2) * 2048;
                #pragma unroll
                for (int kk = 0; kk < 4; ++kk) avA[kk] = *(const bf16x8*)(p + kk * 512);
            }
            f32x4 sqv = *(const f32x4*)(&sqs[tile * 16 + lg * 4]);
            #pragma unroll
            for (int r = 0; r < 4; ++r) {
                float v0 = fmaf(-2.0f, acc0[r], sqv[r]);
                bp0[cnt0] = v0;
                cnt0 += (int)(v0 < thr0);
                float v1 = fmaf(-2.0f, acc1[r], sqv[r]);
                bp1[cnt1] = v1;
                cnt1 += (int)(v1 < thr1);
            }
            if (__any(cnt0 >= TRIG)) { compactB(vals[0], bp0, cnt0); thr0 = vals[0][K2 - 1]; cnt0 = 0; }
            if (__any(cnt1 >= TRIG)) { compactB(vals[1], bp1, cnt1); thr1 = vals[1][K2 - 1]; cnt1 = 0; }
        }
        // ---- odd tile (avB) ----
        {
            f32x4 acc0 = {0.f,0.f,0.f,0.f}, acc1 = {0.f,0.f,0.f,0.f};
            #pragma unroll
            for (int kk = 0; kk < 4; ++kk) {
                acc0 = __builtin_amdgcn_mfma_f32_16x16x32_bf16(avB[kk], bq[0][kk], acc0, 0, 0, 0);
                acc1 = __builtin_amdgcn_mfma_f32_16x16x32_bf16(avB[kk], bq[1][kk], acc1, 0, 0, 0);
            }
            if (tile + 3 < 32) {
                const unsigned short* p = zcl + (size_t)(tile + 3) * 2048;
                #pragma unroll
                for (int kk = 0; kk < 4; ++kk) avB[kk] = *(const bf16x8*)(p + kk * 512);
            }
            f32x4 sqv = *(const f32x4*)(&sqs[(tile + 1) * 16 + lg * 4]);
            #pragma unroll
            for (int r = 0; r < 4; ++r) {
                float v0 = fmaf(-2.0f, acc0[r], sqv[r]);
                bp0[cnt0] = v0;
                cnt0 += (int)(v0 < thr0);
                float v1 = fmaf(-2.0f, acc1[r], sqv[r]);
                bp1[cnt1] = v1;
                cnt1 += (int)(v1 < thr1);
            }
            if (__any(cnt0 >= TRIG)) { compactB(vals[0], bp0, cnt0); thr0 = vals[0][K2 - 1]; cnt0 = 0; }
            if (__any(cnt1 >= TRIG)) { compactB(vals[1], bp1, cnt1); thr1 = vals[1][K2 - 1]; cnt1 = 0; }
        }
    }
    compactB(vals[0], bp0, cnt0);
    compactB(vals[1], bp1, cnt1);

    // cross-lane-group merge: ^16 min-trick -> bitonic sort -> ^32 min-trick
    #pragma unroll
    for (int qt = 0; qt < 2; ++qt) {
        float wk[K2];
        #pragma unroll
        for (int i = 0; i < K2; ++i) {
            float o = __shfl_xor(vals[qt][K2 - 1 - i], 16);
            wk[i] = fminf(vals[qt][i], o);
        }
        sortBitonic11(wk);
        float m1[K2];
        #pragma unroll
        for (int i = 0; i < K2; ++i) {
            float o = __shfl_xor(wk[K2 - 1 - i], 32);
            m1[i] = fminf(wk[i], o);
        }
        if (lg == 0) {
            const int qid = (qt == 0) ? qid0 : qid1;
            float* dst = part + ((size_t)split * NROWS + qid) * K2;
            #pragma unroll
            for (int i = 0; i < K2; ++i) dst[i] = m1[i];
        }
    }
}

// ---------------- K3: merge 16 partial 11-lists (2 threads/q); drop min (self) ----------------
__global__ __launch_bounds__(256) void k_merge(
    const float* __restrict__ part, const float* __restrict__ sq,
    float* __restrict__ sumk, float* __restrict__ total)
{
    __shared__ float xb[128][K2 + 1];
    __shared__ float red[4];
    const int t = threadIdx.x;
    const int qi = t & 127, hf = t >> 7;
    const int q = blockIdx.x * 128 + qi;

    float vals[K2];
    #pragma unroll
    for (int i = 0; i < K2; ++i) vals[i] = BIGF;
    for (int seg = hf * 8; seg < hf * 8 + 8; ++seg) {
        const float* p = part + ((size_t)seg * NROWS + q) * K2;
        #pragma unroll
        for (int i = 0; i < K2; ++i) {
            float tv = p[i];
            if (tv < vals[K2 - 1]) insert11(vals, tv);
        }
    }
    if (hf) {
        #pragma unroll
        for (int i = 0; i < K2; ++i) xb[qi][i] = vals[i];
    }
    __syncthreads();
    float sum = 0.f;
    if (!hf) {
        #pragma unroll
        for (int i = 0; i < K2; ++i) {
            float tv = xb[qi][i];
            if (tv < vals[K2 - 1]) insert11(vals, tv);
        }
        float sqq = sq[q];
        #pragma unroll
        for (int i = 1; i < K2; ++i) {          // skip vals[0] = self
            float raw = sqq + vals[i];
            sum += (raw > 0.f) ? sqrtf(raw) : 0.f;
        }
        sumk[q] = sum;
    }
    #pragma unroll
    for (int off = 32; off > 0; off >>= 1) sum += __shfl_down(sum, off);
    if ((t & 63) == 0) red[t >> 6] = sum;
    __syncthreads();
    if (t == 0) atomicAdd(total, red[0] + red[1] + red[2] + red[3]);
}

// ---------------- K4: finalize ----------------
__global__ __launch_bounds__(256) void k_final(
    const float* __restrict__ sumk, const float* __restrict__ alpha,
    const float* __restrict__ total, float* __restrict__ out)
{
    const int q = blockIdx.x * 256 + threadIdx.x;
    float mean = (*total) * (1.0f / NROWS);
    float m2 = mean * mean;
    float sk = sumk[q];
    float x = (sk * sk) / m2;
    float knn = EPS_CONST / (x + EPS_CONST);
    float rep = 1.0f / (sqrtf(knn) + C_CONST);
    float a = alpha[q];
    a = fminf(fmaxf(a, 1.0f), L_CONST);
    out[q] = rep * a;
}

extern "C" void kernel_launch(void* const* d_in, const int* in_sizes, int n_in,
                              void* d_out, int out_size, void* d_ws, size_t ws_size,
                              hipStream_t stream) {
    const float* s   = (const float*)d_in[0];
    const float* w1  = (const float*)d_in[1];
    const float* b1  = (const float*)d_in[2];
    const float* w2  = (const float*)d_in[3];
    const float* b2  = (const float*)d_in[4];
    const float* w3  = (const float*)d_in[5];
    const float* b3  = (const float*)d_in[6];
    const float* wt1 = (const float*)d_in[7];
    const float* bt1 = (const float*)d_in[8];
    const float* wt2 = (const float*)d_in[9];
    const float* bt2 = (const float*)d_in[10];
    const float* wt3 = (const float*)d_in[11];
    const float* bt3 = (const float*)d_in[12];
    const float* wz1 = (const float*)d_in[13];
    const float* bz1 = (const float*)d_in[14];
    const float* wz2 = (const float*)d_in[15];
    const float* bz2 = (const float*)d_in[16];
    const float* wz3 = (const float*)d_in[17];
    const float* bz3 = (const float*)d_in[18];

    char* ws = (char*)d_ws;
    unsigned short* zf  = (unsigned short*)(ws);                // 512*4*64*8*2   = 2097152
    float* sq    = (float*)(ws + 2097152);                      // 32768
    float* alpha = (float*)(ws + 2129920);                      // 32768
    float* part  = (float*)(ws + 2162688);                      // 16*8192*11*4 = 5767168
    float* sumk  = (float*)(ws + 7929856);                      // 32768
    float* total = (float*)(ws + 7962624);                      // 256
    unsigned short* h1f = (unsigned short*)(ws + 7962880);      // 512*12*64*16*2 = 12582912
    unsigned short* h2f = (unsigned short*)(ws + 20545792);     // 512*6*64*16*2  = 6291456
    unsigned short* sf  = (unsigned short*)(ws + 26837248);     // 512*16*64*16*2 = 16777216
    unsigned short* w1f = (unsigned short*)(ws + 43614464);     // 24*16*64*16*2  = 786432
    unsigned short* w2f = (unsigned short*)(ws + 44400896);     // 12*12*64*16*2  = 294912
    unsigned short* w3f = (unsigned short*)(ws + 44695808);     // 9*6*64*16*2    = 110592
    float* b1c = (float*)(ws + 44806400);
    float* b2c = (float*)(ws + 44807936);
    float* b3c = (float*)(ws + 44808704);

    hipMemsetAsync(total, 0, sizeof(float), stream);

    k_prep<<<2195, 256, 0, stream>>>(s,
                                     w1, wt1, wz1, w2, wt2, wz2, w3, wt3, wz3,
                                     b1, bt1, bz1, b2, bt2, bz2, b3, bt3, bz3,
                                     sf, w1f, w2f, w3f, b1c, b2c, b3c);
    k_gemm1<<<512, 256, 0, stream>>>(sf, w1f, b1c, h1f);
    k_gemm2<<<512, 256, 0, stream>>>(h1f, w2f, b2c, h2f);
    k_gemm3<<<512, 256, 0, stream>>>(h2f, w3f, b3c, zf, sq, alpha);
    k_pairs<<<1024, 256, 0, stream>>>(zf, sq, part);
    k_merge<<<64, 256, 0, stream>>>(part, sq, sumk, total);
    k_final<<<32, 256, 0, stream>>>(sumk, alpha, total, (float*)d_out);
}

// Round 8
// 120.604 us; speedup vs baseline: 2.5339x; 1.1953x over previous
//
#include <hip/hip_runtime.h>
#include <hip/hip_bf16.h>

#define NROWS 8192
#define FDIM 128
#define KNN 10
#define K2 11
#define C_CONST 1.0e-3f
#define L_CONST 5.0f
#define EPS_CONST 1.0e-3f
#define BIGF 3.0e38f
#define BCAP 17
#define TRIG 13

typedef float f32x4 __attribute__((ext_vector_type(4)));
typedef __bf16 bf16x8 __attribute__((ext_vector_type(8)));
typedef unsigned short ushort4v __attribute__((ext_vector_type(4)));
typedef unsigned short ushort8v __attribute__((ext_vector_type(8)));

__device__ __forceinline__ unsigned short f32_to_bf16_rne(float f) {
    unsigned int x = __float_as_uint(f);
    unsigned int lsb = (x >> 16) & 1u;
    x += 0x7fffu + lsb;
    return (unsigned short)(x >> 16);
}

__device__ __forceinline__ void split_bf16(float v, unsigned short& h, unsigned short& l) {
    unsigned short hh = f32_to_bf16_rne(v);
    float hf = __uint_as_float(((unsigned int)hh) << 16);
    h = hh;
    l = f32_to_bf16_rne(v - hf);
}

__device__ __forceinline__ void insert11(float* v, float tv) {
    #pragma unroll
    for (int u = 0; u < K2; ++u) {
        float lo = fminf(v[u], tv);
        tv = fmaxf(v[u], tv);
        v[u] = lo;
    }
}

__device__ __forceinline__ void compactB(float* v, const float* bp, int cnt) {
    #pragma unroll
    for (int i = 0; i < 16; ++i) {
        float tv = (i < cnt) ? bp[i] : BIGF;
        insert11(v, tv);
    }
}

__device__ __forceinline__ void ce(float& a, float& b) {
    float lo = fminf(a, b), hi = fmaxf(a, b); a = lo; b = hi;
}
__device__ __forceinline__ void sortBitonic11(float* w) {
    ce(w[0],w[8]); ce(w[1],w[9]); ce(w[2],w[10]);
    ce(w[0],w[4]); ce(w[1],w[5]); ce(w[2],w[6]); ce(w[3],w[7]);
    ce(w[0],w[2]); ce(w[1],w[3]); ce(w[4],w[6]); ce(w[5],w[7]); ce(w[8],w[10]);
    ce(w[0],w[1]); ce(w[2],w[3]); ce(w[4],w[5]); ce(w[6],w[7]); ce(w[8],w[9]);
}

// ---------------- K0: weight prep only (fragment-major hi/lo) ----------------
__global__ __launch_bounds__(256) void k_prepw(
    const float* __restrict__ w1, const float* __restrict__ wt1, const float* __restrict__ wz1,
    const float* __restrict__ w2, const float* __restrict__ wt2, const float* __restrict__ wz2,
    const float* __restrict__ w3, const float* __restrict__ wt3, const float* __restrict__ wz3,
    const float* __restrict__ b1, const float* __restrict__ bt1, const float* __restrict__ bz1,
    const float* __restrict__ b2, const float* __restrict__ bt2, const float* __restrict__ bz2,
    const float* __restrict__ b3, const float* __restrict__ bt3, const float* __restrict__ bz3,
    unsigned short* __restrict__ w1f, unsigned short* __restrict__ w2f,
    unsigned short* __restrict__ w3f,
    float* __restrict__ b1c, float* __restrict__ b2c, float* __restrict__ b3c)
{
    const int b = blockIdx.x;
    const int t = threadIdx.x;
    const int wv = t >> 6, lane = t & 63;
    const int l15 = lane & 15, lg = lane >> 4;

    if (b < 96) {
        // W1cat [384][512]: nt 0..23, kt 0..15
        const int w = b * 4 + wv;
        const int nt = w >> 4, kt = w & 15;
        const int n = nt * 16 + l15, k = kt * 32 + lg * 8;
        const float* src = (n < 128) ? (w1 + (size_t)n * 512 + k)
                         : (n < 256) ? (wt1 + (size_t)(n - 128) * 512 + k)
                                     : (wz1 + (size_t)(n - 256) * 512 + k);
        f32x4 a = *(const f32x4*)src;
        f32x4 c = *(const f32x4*)(src + 4);
        ushort8v h, l;
        #pragma unroll
        for (int j = 0; j < 4; ++j) {
            unsigned short hh, ll;
            split_bf16(a[j], hh, ll); h[j] = hh; l[j] = ll;
            split_bf16(c[j], hh, ll); h[4 + j] = hh; l[4 + j] = ll;
        }
        unsigned short* dst = w1f + ((size_t)(nt * 16 + kt) * 64 + lane) * 16;
        *(ushort8v*)dst = h;
        *(ushort8v*)(dst + 8) = l;
    } else if (b < 132) {
        // W2cat [192][384] block-diag: nt 0..11, kt 0..11
        const int w = (b - 96) * 4 + wv;
        const int nt = w / 12, kt = w % 12;
        const int n = nt * 16 + l15, k = kt * 32 + lg * 8;
        f32x4 a = {0.f,0.f,0.f,0.f}, c = {0.f,0.f,0.f,0.f};
        if (n < 64)       { if (k < 128)             { const float* p = w2  + (size_t)n * 128 + k;                 a = *(const f32x4*)p; c = *(const f32x4*)(p + 4); } }
        else if (n < 128) { if (k >= 128 && k < 256) { const float* p = wt2 + (size_t)(n - 64) * 128 + (k - 128);  a = *(const f32x4*)p; c = *(const f32x4*)(p + 4); } }
        else              { if (k >= 256)            { const float* p = wz2 + (size_t)(n - 128) * 128 + (k - 256); a = *(const f32x4*)p; c = *(const f32x4*)(p + 4); } }
        ushort8v h, l;
        #pragma unroll
        for (int j = 0; j < 4; ++j) {
            unsigned short hh, ll;
            split_bf16(a[j], hh, ll); h[j] = hh; l[j] = ll;
            split_bf16(c[j], hh, ll); h[4 + j] = hh; l[4 + j] = ll;
        }
        unsigned short* dst = w2f + ((size_t)(nt * 12 + kt) * 64 + lane) * 16;
        *(ushort8v*)dst = h;
        *(ushort8v*)(dst + 8) = l;
    } else if (b < 146) {
        // W3cat [144][192]: nt 0..8, kt 0..5 (54 waves)
        const int w = (b - 132) * 4 + wv;
        if (w < 54) {
            const int nt = w / 6, kt = w % 6;
            const int n = nt * 16 + l15, k = kt * 32 + lg * 8;
            f32x4 a = {0.f,0.f,0.f,0.f}, c = {0.f,0.f,0.f,0.f};
            if (n == 0)                  { if (k < 64)             { const float* p = w3 + k;                                   a = *(const f32x4*)p; c = *(const f32x4*)(p + 4); } }
            else if (n == 1)             { if (k >= 64 && k < 128) { const float* p = wt3 + (k - 64);                           a = *(const f32x4*)p; c = *(const f32x4*)(p + 4); } }
            else if (n >= 16 && n < 144) { if (k >= 128)           { const float* p = wz3 + (size_t)(n - 16) * 64 + (k - 128);  a = *(const f32x4*)p; c = *(const f32x4*)(p + 4); } }
            ushort8v h, l;
            #pragma unroll
            for (int j = 0; j < 4; ++j) {
                unsigned short hh, ll;
                split_bf16(a[j], hh, ll); h[j] = hh; l[j] = ll;
                split_bf16(c[j], hh, ll); h[4 + j] = hh; l[4 + j] = ll;
            }
            unsigned short* dst = w3f + ((size_t)(nt * 6 + kt) * 64 + lane) * 16;
            *(ushort8v*)dst = h;
            *(ushort8v*)(dst + 8) = l;
        }
    } else {
        for (int i = t; i < 720; i += 256) {
            if (i < 384)      b1c[i] = (i < 128) ? b1[i] : (i < 256) ? bt1[i - 128] : bz1[i - 256];
            else if (i < 576) { int j = i - 384; b2c[j] = (j < 64) ? b2[j] : (j < 128) ? bt2[j - 64] : bz2[j - 128]; }
            else              { int j = i - 576; b3c[j] = (j == 0) ? b3[0] : (j == 1) ? bt3[0] : (j < 16) ? 0.f : bz3[j - 16]; }
        }
    }
}

// ---------------- K1: fused 3-layer MLP, all activations in LDS ----------------
// 512 blocks x 512 thr (8 waves); block = m-tile (16 rows of s).
__global__ __launch_bounds__(512, 4) void k_mlp(
    const float* __restrict__ s,
    const unsigned short* __restrict__ w1f, const unsigned short* __restrict__ w2f,
    const unsigned short* __restrict__ w3f,
    const float* __restrict__ b1c, const float* __restrict__ b2c, const float* __restrict__ b3c,
    unsigned short* __restrict__ zf, float* __restrict__ sq, float* __restrict__ alpha)
{
    __shared__ unsigned short sfrag[16][64][16];   // 32 KB
    __shared__ unsigned short h1frag[12][64][16];  // 24 KB
    __shared__ unsigned short h2frag[6][64][16];   // 12 KB
    __shared__ float sred[8][16];

    const int t = threadIdx.x;
    const int lane = t & 63, wv = t >> 6;
    const int l15 = lane & 15, lg = lane >> 4;
    const int mt = blockIdx.x;

    // ---- phase 0: stage s rows as hi/lo fragments in LDS ----
    #pragma unroll
    for (int si = 0; si < 2; ++si) {
        const int slot = t + si * 512;
        const int kt = slot >> 6, ln = slot & 63;
        const int r = ln & 15, g = ln >> 4;
        const float* src = s + (size_t)(mt * 16 + r) * 512 + kt * 32 + g * 8;
        f32x4 a = *(const f32x4*)src;
        f32x4 c = *(const f32x4*)(src + 4);
        ushort8v h, l;
        #pragma unroll
        for (int j = 0; j < 4; ++j) {
            unsigned short hh, ll;
            split_bf16(a[j], hh, ll); h[j] = hh; l[j] = ll;
            split_bf16(c[j], hh, ll); h[4 + j] = hh; l[4 + j] = ll;
        }
        *(ushort8v*)&sfrag[kt][ln][0] = h;
        *(ushort8v*)&sfrag[kt][ln][8] = l;
    }
    __syncthreads();

    // ---- phase 1: h1 = relu(s @ W1cat^T + b1c); 8 waves x 3 n-tiles ----
    {
        f32x4 acc[3];
        #pragma unroll
        for (int i = 0; i < 3; ++i) acc[i] = (f32x4){0.f, 0.f, 0.f, 0.f};
        for (int kt = 0; kt < 16; ++kt) {
            bf16x8 axh = *(const bf16x8*)&sfrag[kt][lane][0];
            bf16x8 axl = *(const bf16x8*)&sfrag[kt][lane][8];
            #pragma unroll
            for (int i = 0; i < 3; ++i) {
                const unsigned short* wp = w1f + ((size_t)((wv * 3 + i) * 16 + kt) * 64 + lane) * 16;
                bf16x8 bh = *(const bf16x8*)wp;
                bf16x8 bl = *(const bf16x8*)(wp + 8);
                acc[i] = __builtin_amdgcn_mfma_f32_16x16x32_bf16(bh, axh, acc[i], 0, 0, 0);
                acc[i] = __builtin_amdgcn_mfma_f32_16x16x32_bf16(bl, axh, acc[i], 0, 0, 0);
                acc[i] = __builtin_amdgcn_mfma_f32_16x16x32_bf16(bh, axl, acc[i], 0, 0, 0);
            }
        }
        #pragma unroll
        for (int i = 0; i < 3; ++i) {
            const int ntile = wv * 3 + i;
            const int n0 = ntile * 16 + lg * 4;
            f32x4 bv = *(const f32x4*)(b1c + n0);
            f32x4 v = acc[i] + bv;
            ushort4v vh, vl;
            #pragma unroll
            for (int r = 0; r < 4; ++r) {
                float x = fmaxf(v[r], 0.f);
                unsigned short hh, ll; split_bf16(x, hh, ll);
                vh[r] = hh; vl[r] = ll;
            }
            const int ch = ntile * 2 + (lg >> 1);
            const int kt2 = ch >> 2;
            const int lane2 = (ch & 3) * 16 + l15;
            const int e0 = (lg & 1) * 4;
            *(ushort4v*)&h1frag[kt2][lane2][e0] = vh;
            *(ushort4v*)&h1frag[kt2][lane2][e0 + 8] = vl;
        }
    }
    __syncthreads();

    // ---- phase 2: h2 = relu(h1 @ W2cat^T + b2c); waves 0-3: 2 tiles, 4-7: 1 tile ----
    {
        const int c2 = (wv < 4) ? 2 : 1;
        f32x4 acc[2];
        #pragma unroll
        for (int i = 0; i < 2; ++i) acc[i] = (f32x4){0.f, 0.f, 0.f, 0.f};
        for (int kt = 0; kt < 12; ++kt) {
            bf16x8 axh = *(const bf16x8*)&h1frag[kt][lane][0];
            bf16x8 axl = *(const bf16x8*)&h1frag[kt][lane][8];
            #pragma unroll
            for (int i = 0; i < 2; ++i) {
                if (i < c2) {
                    const int nt = (wv < 4) ? (wv * 2 + i) : (8 + (wv - 4));
                    const unsigned short* wp = w2f + ((size_t)(nt * 12 + kt) * 64 + lane) * 16;
                    bf16x8 bh = *(const bf16x8*)wp;
                    bf16x8 bl = *(const bf16x8*)(wp + 8);
                    acc[i] = __builtin_amdgcn_mfma_f32_16x16x32_bf16(bh, axh, acc[i], 0, 0, 0);
                    acc[i] = __builtin_amdgcn_mfma_f32_16x16x32_bf16(bl, axh, acc[i], 0, 0, 0);
                    acc[i] = __builtin_amdgcn_mfma_f32_16x16x32_bf16(bh, axl, acc[i], 0, 0, 0);
                }
            }
        }
        #pragma unroll
        for (int i = 0; i < 2; ++i) {
            if (i < c2) {
                const int ntile = (wv < 4) ? (wv * 2 + i) : (8 + (wv - 4));
                const int n0 = ntile * 16 + lg * 4;
                f32x4 bv = *(const f32x4*)(b2c + n0);
                f32x4 v = acc[i] + bv;
                ushort4v vh, vl;
                #pragma unroll
                for (int r = 0; r < 4; ++r) {
                    float x = fmaxf(v[r], 0.f);
                    unsigned short hh, ll; split_bf16(x, hh, ll);
                    vh[r] = hh; vl[r] = ll;
                }
                const int ch = ntile * 2 + (lg >> 1);
                const int kt2 = ch >> 2;
                const int lane2 = (ch & 3) * 16 + l15;
                const int e0 = (lg & 1) * 4;
                *(ushort4v*)&h2frag[kt2][lane2][e0] = vh;
                *(ushort4v*)&h2frag[kt2][lane2][e0 + 8] = vl;
            }
        }
    }
    __syncthreads();

    // ---- phase 3: out144 = h2 @ W3cat^T + b3c -> zf / sq / alpha ----
    {
        const int c3 = (wv == 0) ? 2 : 1;   // wave 0: tiles {0, 8}; wave w: tile w
        f32x4 acc[2];
        #pragma unroll
        for (int i = 0; i < 2; ++i) acc[i] = (f32x4){0.f, 0.f, 0.f, 0.f};
        for (int kt = 0; kt < 6; ++kt) {
            bf16x8 axh = *(const bf16x8*)&h2frag[kt][lane][0];
            bf16x8 axl = *(const bf16x8*)&h2frag[kt][lane][8];
            #pragma unroll
            for (int i = 0; i < 2; ++i) {
                if (i < c3) {
                    const int nt = (i == 0) ? wv : 8;
                    const unsigned short* wp = w3f + ((size_t)(nt * 6 + kt) * 64 + lane) * 16;
                    bf16x8 bh = *(const bf16x8*)wp;
                    bf16x8 bl = *(const bf16x8*)(wp + 8);
                    acc[i] = __builtin_amdgcn_mfma_f32_16x16x32_bf16(bh, axh, acc[i], 0, 0, 0);
                    acc[i] = __builtin_amdgcn_mfma_f32_16x16x32_bf16(bl, axh, acc[i], 0, 0, 0);
                    acc[i] = __builtin_amdgcn_mfma_f32_16x16x32_bf16(bh, axl, acc[i], 0, 0, 0);
                }
            }
        }
        float ssq = 0.f;
        float pred = 0.f, tgt = 0.f;
        #pragma unroll
        for (int i = 0; i < 2; ++i) {
            if (i < c3) {
                const int ntg = (i == 0) ? wv : 8;
                const int n0 = ntg * 16 + lg * 4;
                f32x4 bv = *(const f32x4*)(b3c + n0);
                f32x4 v = acc[i] + bv;
                if (ntg == 0) {
                    if (lg == 0) { pred = v.x; tgt = v.y; }
                } else {
                    ushort4v zu;
                    #pragma unroll
                    for (int r = 0; r < 4; ++r) {
                        unsigned short us = f32_to_bf16_rne(v[r]);
                        float zf32 = __uint_as_float(((unsigned int)us) << 16);
                        ssq += zf32 * zf32;
                        zu[r] = us;
                    }
                    const int ch = (ntg - 1) * 2 + (lg >> 1);
                    const int kk = ch >> 2;
                    const int lane2 = (ch & 3) * 16 + l15;
                    const int e0 = (lg & 1) * 4;
                    *(ushort4v*)(zf + ((size_t)(mt * 4 + kk) * 64 + lane2) * 8 + e0) = zu;
                }
            }
        }
        ssq += __shfl_xor(ssq, 16);
        ssq += __shfl_xor(ssq, 32);
        if (lg == 0) sred[wv][l15] = ssq;
        __syncthreads();
        if (t < 16) {
            float sm = 0.f;
            #pragma unroll
            for (int w8 = 0; w8 < 8; ++w8) sm += sred[w8][t];
            sq[mt * 16 + t] = sm;
        }
        if (wv == 0 && lg == 0) {
            float d = pred - tgt;
            alpha[mt * 16 + l15] = d * d;
        }
    }
}

// ---------------- K2: pairwise + threshold-filtered top-11, fragment-major zf ----------------
__global__ __launch_bounds__(256, 4) void k_pairs(
    const unsigned short* __restrict__ zf, const float* __restrict__ sq,
    float* __restrict__ part)
{
    __shared__ float buf[4][2][64][BCAP];
    __shared__ float sqs[512];
    const int t = threadIdx.x;
    const int lane = t & 63;
    const int wv = t >> 6;
    const int split = blockIdx.x & 15;
    const int qg = (blockIdx.x >> 4) * 4 + wv;
    const int l15 = lane & 15, lg = lane >> 4;
    const int c0 = split * 512;

    sqs[t] = sq[c0 + t];
    sqs[t + 256] = sq[c0 + t + 256];
    __syncthreads();

    float* bp0 = &buf[wv][0][lane][0];
    float* bp1 = &buf[wv][1][lane][0];

    const int qid0 = qg * 32 + l15;
    const int qid1 = qg * 32 + 16 + l15;
    bf16x8 bq[2][4];
    {
        const unsigned short* qp0 = zf + ((size_t)(qg * 2) * 256 + lane) * 8;
        const unsigned short* qp1 = zf + ((size_t)(qg * 2 + 1) * 256 + lane) * 8;
        #pragma unroll
        for (int kk = 0; kk < 4; ++kk) {
            bq[0][kk] = *(const bf16x8*)(qp0 + kk * 512);
            bq[1][kk] = *(const bf16x8*)(qp1 + kk * 512);
        }
    }

    float vals[2][K2];
    #pragma unroll
    for (int qt = 0; qt < 2; ++qt)
        #pragma unroll
        for (int i = 0; i < K2; ++i) vals[qt][i] = BIGF;
    float thr0 = BIGF, thr1 = BIGF;
    int cnt0 = 0, cnt1 = 0;

    const unsigned short* zcl = zf + ((size_t)(split * 32) * 256 + lane) * 8;
    bf16x8 avA[4], avB[4];
    #pragma unroll
    for (int kk = 0; kk < 4; ++kk) avA[kk] = *(const bf16x8*)(zcl + kk * 512);
    #pragma unroll
    for (int kk = 0; kk < 4; ++kk) avB[kk] = *(const bf16x8*)(zcl + 2048 + kk * 512);

    for (int tile = 0; tile < 32; tile += 2) {
        {
            f32x4 acc0 = {0.f,0.f,0.f,0.f}, acc1 = {0.f,0.f,0.f,0.f};
            #pragma unroll
            for (int kk = 0; kk < 4; ++kk) {
                acc0 = __builtin_amdgcn_mfma_f32_16x16x32_bf16(avA[kk], bq[0][kk], acc0, 0, 0, 0);
                acc1 = __builtin_amdgcn_mfma_f32_16x16x32_bf16(avA[kk], bq[1][kk], acc1, 0, 0, 0);
            }
            if (tile + 2 < 32) {
                const unsigned short* p = zcl + (size_t)(tile + 2) * 2048;
                #pragma unroll
                for (int kk = 0; kk < 4; ++kk) avA[kk] = *(const bf16x8*)(p + kk * 512);
            }
            f32x4 sqv = *(const f32x4*)(&sqs[tile * 16 + lg * 4]);
            #pragma unroll
            for (int r = 0; r < 4; ++r) {
                float v0 = fmaf(-2.0f, acc0[r], sqv[r]);
                bp0[cnt0] = v0;
                cnt0 += (int)(v0 < thr0);
                float v1 = fmaf(-2.0f, acc1[r], sqv[r]);
                bp1[cnt1] = v1;
                cnt1 += (int)(v1 < thr1);
            }
            if (__any(cnt0 >= TRIG)) { compactB(vals[0], bp0, cnt0); thr0 = vals[0][K2 - 1]; cnt0 = 0; }
            if (__any(cnt1 >= TRIG)) { compactB(vals[1], bp1, cnt1); thr1 = vals[1][K2 - 1]; cnt1 = 0; }
        }
        {
            f32x4 acc0 = {0.f,0.f,0.f,0.f}, acc1 = {0.f,0.f,0.f,0.f};
            #pragma unroll
            for (int kk = 0; kk < 4; ++kk) {
                acc0 = __builtin_amdgcn_mfma_f32_16x16x32_bf16(avB[kk], bq[0][kk], acc0, 0, 0, 0);
                acc1 = __builtin_amdgcn_mfma_f32_16x16x32_bf16(avB[kk], bq[1][kk], acc1, 0, 0, 0);
            }
            if (tile + 3 < 32) {
                const unsigned short* p = zcl + (size_t)(tile + 3) * 2048;
                #pragma unroll
                for (int kk = 0; kk < 4; ++kk) avB[kk] = *(const bf16x8*)(p + kk * 512);
            }
            f32x4 sqv = *(const f32x4*)(&sqs[(tile + 1) * 16 + lg * 4]);
            #pragma unroll
            for (int r = 0; r < 4; ++r) {
                float v0 = fmaf(-2.0f, acc0[r], sqv[r]);
                bp0[cnt0] = v0;
                cnt0 += (int)(v0 < thr0);
                float v1 = fmaf(-2.0f, acc1[r], sqv[r]);
                bp1[cnt1] = v1;
                cnt1 += (int)(v1 < thr1);
            }
            if (__any(cnt0 >= TRIG)) { compactB(vals[0], bp0, cnt0); thr0 = vals[0][K2 - 1]; cnt0 = 0; }
            if (__any(cnt1 >= TRIG)) { compactB(vals[1], bp1, cnt1); thr1 = vals[1][K2 - 1]; cnt1 = 0; }
        }
    }
    compactB(vals[0], bp0, cnt0);
    compactB(vals[1], bp1, cnt1);

    #pragma unroll
    for (int qt = 0; qt < 2; ++qt) {
        float wk[K2];
        #pragma unroll
        for (int i = 0; i < K2; ++i) {
            float o = __shfl_xor(vals[qt][K2 - 1 - i], 16);
            wk[i] = fminf(vals[qt][i], o);
        }
        sortBitonic11(wk);
        float m1[K2];
        #pragma unroll
        for (int i = 0; i < K2; ++i) {
            float o = __shfl_xor(wk[K2 - 1 - i], 32);
            m1[i] = fminf(wk[i], o);
        }
        if (lg == 0) {
            const int qid = (qt == 0) ? qid0 : qid1;
            float* dst = part + ((size_t)split * NROWS + qid) * K2;
            #pragma unroll
            for (int i = 0; i < K2; ++i) dst[i] = m1[i];
        }
    }
}

// ---------------- K3: merge 16 partial 11-lists (2 threads/q); drop min (self) ----------------
__global__ __launch_bounds__(256) void k_merge(
    const float* __restrict__ part, const float* __restrict__ sq,
    float* __restrict__ sumk, float* __restrict__ total)
{
    __shared__ float xb[128][K2 + 1];
    __shared__ float red[4];
    const int t = threadIdx.x;
    const int qi = t & 127, hf = t >> 7;
    const int q = blockIdx.x * 128 + qi;

    float vals[K2];
    #pragma unroll
    for (int i = 0; i < K2; ++i) vals[i] = BIGF;
    for (int seg = hf * 8; seg < hf * 8 + 8; ++seg) {
        const float* p = part + ((size_t)seg * NROWS + q) * K2;
        #pragma unroll
        for (int i = 0; i < K2; ++i) {
            float tv = p[i];
            if (tv < vals[K2 - 1]) insert11(vals, tv);
        }
    }
    if (hf) {
        #pragma unroll
        for (int i = 0; i < K2; ++i) xb[qi][i] = vals[i];
    }
    __syncthreads();
    float sum = 0.f;
    if (!hf) {
        #pragma unroll
        for (int i = 0; i < K2; ++i) {
            float tv = xb[qi][i];
            if (tv < vals[K2 - 1]) insert11(vals, tv);
        }
        float sqq = sq[q];
        #pragma unroll
        for (int i = 1; i < K2; ++i) {
            float raw = sqq + vals[i];
            sum += (raw > 0.f) ? sqrtf(raw) : 0.f;
        }
        sumk[q] = sum;
    }
    #pragma unroll
    for (int off = 32; off > 0; off >>= 1) sum += __shfl_down(sum, off);
    if ((t & 63) == 0) red[t >> 6] = sum;
    __syncthreads();
    if (t == 0) atomicAdd(total, red[0] + red[1] + red[2] + red[3]);
}

// ---------------- K4: finalize ----------------
__global__ __launch_bounds__(256) void k_final(
    const float* __restrict__ sumk, const float* __restrict__ alpha,
    const float* __restrict__ total, float* __restrict__ out)
{
    const int q = blockIdx.x * 256 + threadIdx.x;
    float mean = (*total) * (1.0f / NROWS);
    float m2 = mean * mean;
    float sk = sumk[q];
    float x = (sk * sk) / m2;
    float knn = EPS_CONST / (x + EPS_CONST);
    float rep = 1.0f / (sqrtf(knn) + C_CONST);
    float a = alpha[q];
    a = fminf(fmaxf(a, 1.0f), L_CONST);
    out[q] = rep * a;
}

extern "C" void kernel_launch(void* const* d_in, const int* in_sizes, int n_in,
                              void* d_out, int out_size, void* d_ws, size_t ws_size,
                              hipStream_t stream) {
    const float* s   = (const float*)d_in[0];
    const float* w1  = (const float*)d_in[1];
    const float* b1  = (const float*)d_in[2];
    const float* w2  = (const float*)d_in[3];
    const float* b2  = (const float*)d_in[4];
    const float* w3  = (const float*)d_in[5];
    const float* b3  = (const float*)d_in[6];
    const float* wt1 = (const float*)d_in[7];
    const float* bt1 = (const float*)d_in[8];
    const float* wt2 = (const float*)d_in[9];
    const float* bt2 = (const float*)d_in[10];
    const float* wt3 = (const float*)d_in[11];
    const float* bt3 = (const float*)d_in[12];
    const float* wz1 = (const float*)d_in[13];
    const float* bz1 = (const float*)d_in[14];
    const float* wz2 = (const float*)d_in[15];
    const float* bz2 = (const float*)d_in[16];
    const float* wz3 = (const float*)d_in[17];
    const float* bz3 = (const float*)d_in[18];

    char* ws = (char*)d_ws;
    unsigned short* zf  = (unsigned short*)(ws);                // 2097152
    float* sq    = (float*)(ws + 2097152);                      // 32768
    float* alpha = (float*)(ws + 2129920);                      // 32768
    float* part  = (float*)(ws + 2162688);                      // 16*8192*11*4 = 5767168
    float* sumk  = (float*)(ws + 7929856);                      // 32768
    float* total = (float*)(ws + 7962624);                      // 256
    unsigned short* w1f = (unsigned short*)(ws + 7962880);      // 786432
    unsigned short* w2f = (unsigned short*)(ws + 8749312);      // 294912
    unsigned short* w3f = (unsigned short*)(ws + 9044224);      // 110592
    float* b1c = (float*)(ws + 9154816);
    float* b2c = (float*)(ws + 9156352);
    float* b3c = (float*)(ws + 9157120);

    hipMemsetAsync(total, 0, sizeof(float), stream);

    k_prepw<<<147, 256, 0, stream>>>(w1, wt1, wz1, w2, wt2, wz2, w3, wt3, wz3,
                                     b1, bt1, bz1, b2, bt2, bz2, b3, bt3, bz3,
                                     w1f, w2f, w3f, b1c, b2c, b3c);
    k_mlp<<<512, 512, 0, stream>>>(s, w1f, w2f, w3f, b1c, b2c, b3c, zf, sq, alpha);
    k_pairs<<<1024, 256, 0, stream>>>(zf, sq, part);
    k_merge<<<64, 256, 0, stream>>>(part, sq, sumk, total);
    k_final<<<32, 256, 0, stream>>>(sumk, alpha, total, (float*)d_out);
}

// Round 9
// 112.807 us; speedup vs baseline: 2.7090x; 1.0691x over previous
//
#include <hip/hip_runtime.h>
#include <hip/hip_bf16.h>

#define NROWS 8192
#define FDIM 128
#define KNN 10
#define K2 11
#define C_CONST 1.0e-3f
#define L_CONST 5.0f
#define EPS_CONST 1.0e-3f
#define BIGF 3.0e38f
#define BCAP 17
#define TRIG 13

typedef float f32x4 __attribute__((ext_vector_type(4)));
typedef __bf16 bf16x8 __attribute__((ext_vector_type(8)));
typedef unsigned short ushort4v __attribute__((ext_vector_type(4)));
typedef unsigned short ushort8v __attribute__((ext_vector_type(8)));

__device__ __forceinline__ unsigned short f32_to_bf16_rne(float f) {
    unsigned int x = __float_as_uint(f);
    unsigned int lsb = (x >> 16) & 1u;
    x += 0x7fffu + lsb;
    return (unsigned short)(x >> 16);
}

__device__ __forceinline__ void split_bf16(float v, unsigned short& h, unsigned short& l) {
    unsigned short hh = f32_to_bf16_rne(v);
    float hf = __uint_as_float(((unsigned int)hh) << 16);
    h = hh;
    l = f32_to_bf16_rne(v - hf);
}

__device__ __forceinline__ void insert11(float* v, float tv) {
    #pragma unroll
    for (int u = 0; u < K2; ++u) {
        float lo = fminf(v[u], tv);
        tv = fmaxf(v[u], tv);
        v[u] = lo;
    }
}

__device__ __forceinline__ void compactB(float* v, const float* bp, int cnt) {
    #pragma unroll
    for (int i = 0; i < 16; ++i) {
        float tv = (i < cnt) ? bp[i] : BIGF;
        insert11(v, tv);
    }
}

__device__ __forceinline__ void ce(float& a, float& b) {
    float lo = fminf(a, b), hi = fmaxf(a, b); a = lo; b = hi;
}
__device__ __forceinline__ void sortBitonic11(float* w) {
    ce(w[0],w[8]); ce(w[1],w[9]); ce(w[2],w[10]);
    ce(w[0],w[4]); ce(w[1],w[5]); ce(w[2],w[6]); ce(w[3],w[7]);
    ce(w[0],w[2]); ce(w[1],w[3]); ce(w[4],w[6]); ce(w[5],w[7]); ce(w[8],w[10]);
    ce(w[0],w[1]); ce(w[2],w[3]); ce(w[4],w[5]); ce(w[6],w[7]); ce(w[8],w[9]);
}

// ---------------- K0: weight prep (fragment-major hi/lo) ----------------
__global__ __launch_bounds__(256) void k_prepw(
    const float* __restrict__ w1, const float* __restrict__ wt1, const float* __restrict__ wz1,
    const float* __restrict__ w2, const float* __restrict__ wt2, const float* __restrict__ wz2,
    const float* __restrict__ w3, const float* __restrict__ wt3, const float* __restrict__ wz3,
    const float* __restrict__ b1, const float* __restrict__ bt1, const float* __restrict__ bz1,
    const float* __restrict__ b2, const float* __restrict__ bt2, const float* __restrict__ bz2,
    const float* __restrict__ b3, const float* __restrict__ bt3, const float* __restrict__ bz3,
    unsigned short* __restrict__ w1f, unsigned short* __restrict__ w2f,
    unsigned short* __restrict__ w3f,
    float* __restrict__ b1c, float* __restrict__ b2c, float* __restrict__ b3c)
{
    const int b = blockIdx.x;
    const int t = threadIdx.x;
    const int wv = t >> 6, lane = t & 63;
    const int l15 = lane & 15, lg = lane >> 4;

    if (b < 96) {
        const int w = b * 4 + wv;
        const int nt = w >> 4, kt = w & 15;
        const int n = nt * 16 + l15, k = kt * 32 + lg * 8;
        const float* src = (n < 128) ? (w1 + (size_t)n * 512 + k)
                         : (n < 256) ? (wt1 + (size_t)(n - 128) * 512 + k)
                                     : (wz1 + (size_t)(n - 256) * 512 + k);
        f32x4 a = *(const f32x4*)src;
        f32x4 c = *(const f32x4*)(src + 4);
        ushort8v h, l;
        #pragma unroll
        for (int j = 0; j < 4; ++j) {
            unsigned short hh, ll;
            split_bf16(a[j], hh, ll); h[j] = hh; l[j] = ll;
            split_bf16(c[j], hh, ll); h[4 + j] = hh; l[4 + j] = ll;
        }
        unsigned short* dst = w1f + ((size_t)(nt * 16 + kt) * 64 + lane) * 16;
        *(ushort8v*)dst = h;
        *(ushort8v*)(dst + 8) = l;
    } else if (b < 132) {
        const int w = (b - 96) * 4 + wv;
        const int nt = w / 12, kt = w % 12;
        const int n = nt * 16 + l15, k = kt * 32 + lg * 8;
        f32x4 a = {0.f,0.f,0.f,0.f}, c = {0.f,0.f,0.f,0.f};
        if (n < 64)       { if (k < 128)             { const float* p = w2  + (size_t)n * 128 + k;                 a = *(const f32x4*)p; c = *(const f32x4*)(p + 4); } }
        else if (n < 128) { if (k >= 128 && k < 256) { const float* p = wt2 + (size_t)(n - 64) * 128 + (k - 128);  a = *(const f32x4*)p; c = *(const f32x4*)(p + 4); } }
        else              { if (k >= 256)            { const float* p = wz2 + (size_t)(n - 128) * 128 + (k - 256); a = *(const f32x4*)p; c = *(const f32x4*)(p + 4); } }
        ushort8v h, l;
        #pragma unroll
        for (int j = 0; j < 4; ++j) {
            unsigned short hh, ll;
            split_bf16(a[j], hh, ll); h[j] = hh; l[j] = ll;
            split_bf16(c[j], hh, ll); h[4 + j] = hh; l[4 + j] = ll;
        }
        unsigned short* dst = w2f + ((size_t)(nt * 12 + kt) * 64 + lane) * 16;
        *(ushort8v*)dst = h;
        *(ushort8v*)(dst + 8) = l;
    } else if (b < 146) {
        const int w = (b - 132) * 4 + wv;
        if (w < 54) {
            const int nt = w / 6, kt = w % 6;
            const int n = nt * 16 + l15, k = kt * 32 + lg * 8;
            f32x4 a = {0.f,0.f,0.f,0.f}, c = {0.f,0.f,0.f,0.f};
            if (n == 0)                  { if (k < 64)             { const float* p = w3 + k;                                   a = *(const f32x4*)p; c = *(const f32x4*)(p + 4); } }
            else if (n == 1)             { if (k >= 64 && k < 128) { const float* p = wt3 + (k - 64);                           a = *(const f32x4*)p; c = *(const f32x4*)(p + 4); } }
            else if (n >= 16 && n < 144) { if (k >= 128)           { const float* p = wz3 + (size_t)(n - 16) * 64 + (k - 128);  a = *(const f32x4*)p; c = *(const f32x4*)(p + 4); } }
            ushort8v h, l;
            #pragma unroll
            for (int j = 0; j < 4; ++j) {
                unsigned short hh, ll;
                split_bf16(a[j], hh, ll); h[j] = hh; l[j] = ll;
                split_bf16(c[j], hh, ll); h[4 + j] = hh; l[4 + j] = ll;
            }
            unsigned short* dst = w3f + ((size_t)(nt * 6 + kt) * 64 + lane) * 16;
            *(ushort8v*)dst = h;
            *(ushort8v*)(dst + 8) = l;
        }
    } else {
        for (int i = t; i < 720; i += 256) {
            if (i < 384)      b1c[i] = (i < 128) ? b1[i] : (i < 256) ? bt1[i - 128] : bz1[i - 256];
            else if (i < 576) { int j = i - 384; b2c[j] = (j < 64) ? b2[j] : (j < 128) ? bt2[j - 64] : bz2[j - 128]; }
            else              { int j = i - 576; b3c[j] = (j == 0) ? b3[0] : (j == 1) ? bt3[0] : (j < 16) ? 0.f : bz3[j - 16]; }
        }
    }
}

// ---------------- K1: fused 3-layer MLP, all activations in LDS ----------------
__global__ __launch_bounds__(512, 4) void k_mlp(
    const float* __restrict__ s,
    const unsigned short* __restrict__ w1f, const unsigned short* __restrict__ w2f,
    const unsigned short* __restrict__ w3f,
    const float* __restrict__ b1c, const float* __restrict__ b2c, const float* __restrict__ b3c,
    unsigned short* __restrict__ zf, float* __restrict__ sq, float* __restrict__ alpha)
{
    __shared__ unsigned short sfrag[16][64][16];
    __shared__ unsigned short h1frag[12][64][16];
    __shared__ unsigned short h2frag[6][64][16];
    __shared__ float sred[8][16];

    const int t = threadIdx.x;
    const int lane = t & 63, wv = t >> 6;
    const int l15 = lane & 15, lg = lane >> 4;
    const int mt = blockIdx.x;

    #pragma unroll
    for (int si = 0; si < 2; ++si) {
        const int slot = t + si * 512;
        const int kt = slot >> 6, ln = slot & 63;
        const int r = ln & 15, g = ln >> 4;
        const float* src = s + (size_t)(mt * 16 + r) * 512 + kt * 32 + g * 8;
        f32x4 a = *(const f32x4*)src;
        f32x4 c = *(const f32x4*)(src + 4);
        ushort8v h, l;
        #pragma unroll
        for (int j = 0; j < 4; ++j) {
            unsigned short hh, ll;
            split_bf16(a[j], hh, ll); h[j] = hh; l[j] = ll;
            split_bf16(c[j], hh, ll); h[4 + j] = hh; l[4 + j] = ll;
        }
        *(ushort8v*)&sfrag[kt][ln][0] = h;
        *(ushort8v*)&sfrag[kt][ln][8] = l;
    }
    __syncthreads();

    {
        f32x4 acc[3];
        #pragma unroll
        for (int i = 0; i < 3; ++i) acc[i] = (f32x4){0.f, 0.f, 0.f, 0.f};
        for (int kt = 0; kt < 16; ++kt) {
            bf16x8 axh = *(const bf16x8*)&sfrag[kt][lane][0];
            bf16x8 axl = *(const bf16x8*)&sfrag[kt][lane][8];
            #pragma unroll
            for (int i = 0; i < 3; ++i) {
                const unsigned short* wp = w1f + ((size_t)((wv * 3 + i) * 16 + kt) * 64 + lane) * 16;
                bf16x8 bh = *(const bf16x8*)wp;
                bf16x8 bl = *(const bf16x8*)(wp + 8);
                acc[i] = __builtin_amdgcn_mfma_f32_16x16x32_bf16(bh, axh, acc[i], 0, 0, 0);
                acc[i] = __builtin_amdgcn_mfma_f32_16x16x32_bf16(bl, axh, acc[i], 0, 0, 0);
                acc[i] = __builtin_amdgcn_mfma_f32_16x16x32_bf16(bh, axl, acc[i], 0, 0, 0);
            }
        }
        #pragma unroll
        for (int i = 0; i < 3; ++i) {
            const int ntile = wv * 3 + i;
            const int n0 = ntile * 16 + lg * 4;
            f32x4 bv = *(const f32x4*)(b1c + n0);
            f32x4 v = acc[i] + bv;
            ushort4v vh, vl;
            #pragma unroll
            for (int r = 0; r < 4; ++r) {
                float x = fmaxf(v[r], 0.f);
                unsigned short hh, ll; split_bf16(x, hh, ll);
                vh[r] = hh; vl[r] = ll;
            }
            const int ch = ntile * 2 + (lg >> 1);
            const int kt2 = ch >> 2;
            const int lane2 = (ch & 3) * 16 + l15;
            const int e0 = (lg & 1) * 4;
            *(ushort4v*)&h1frag[kt2][lane2][e0] = vh;
            *(ushort4v*)&h1frag[kt2][lane2][e0 + 8] = vl;
        }
    }
    __syncthreads();

    {
        const int c2 = (wv < 4) ? 2 : 1;
        f32x4 acc[2];
        #pragma unroll
        for (int i = 0; i < 2; ++i) acc[i] = (f32x4){0.f, 0.f, 0.f, 0.f};
        for (int kt = 0; kt < 12; ++kt) {
            bf16x8 axh = *(const bf16x8*)&h1frag[kt][lane][0];
            bf16x8 axl = *(const bf16x8*)&h1frag[kt][lane][8];
            #pragma unroll
            for (int i = 0; i < 2; ++i) {
                if (i < c2) {
                    const int nt = (wv < 4) ? (wv * 2 + i) : (8 + (wv - 4));
                    const unsigned short* wp = w2f + ((size_t)(nt * 12 + kt) * 64 + lane) * 16;
                    bf16x8 bh = *(const bf16x8*)wp;
                    bf16x8 bl = *(const bf16x8*)(wp + 8);
                    acc[i] = __builtin_amdgcn_mfma_f32_16x16x32_bf16(bh, axh, acc[i], 0, 0, 0);
                    acc[i] = __builtin_amdgcn_mfma_f32_16x16x32_bf16(bl, axh, acc[i], 0, 0, 0);
                    acc[i] = __builtin_amdgcn_mfma_f32_16x16x32_bf16(bh, axl, acc[i], 0, 0, 0);
                }
            }
        }
        #pragma unroll
        for (int i = 0; i < 2; ++i) {
            if (i < c2) {
                const int ntile = (wv < 4) ? (wv * 2 + i) : (8 + (wv - 4));
                const int n0 = ntile * 16 + lg * 4;
                f32x4 bv = *(const f32x4*)(b2c + n0);
                f32x4 v = acc[i] + bv;
                ushort4v vh, vl;
                #pragma unroll
                for (int r = 0; r < 4; ++r) {
                    float x = fmaxf(v[r], 0.f);
                    unsigned short hh, ll; split_bf16(x, hh, ll);
                    vh[r] = hh; vl[r] = ll;
                }
                const int ch = ntile * 2 + (lg >> 1);
                const int kt2 = ch >> 2;
                const int lane2 = (ch & 3) * 16 + l15;
                const int e0 = (lg & 1) * 4;
                *(ushort4v*)&h2frag[kt2][lane2][e0] = vh;
                *(ushort4v*)&h2frag[kt2][lane2][e0 + 8] = vl;
            }
        }
    }
    __syncthreads();

    {
        const int c3 = (wv == 0) ? 2 : 1;
        f32x4 acc[2];
        #pragma unroll
        for (int i = 0; i < 2; ++i) acc[i] = (f32x4){0.f, 0.f, 0.f, 0.f};
        for (int kt = 0; kt < 6; ++kt) {
            bf16x8 axh = *(const bf16x8*)&h2frag[kt][lane][0];
            bf16x8 axl = *(const bf16x8*)&h2frag[kt][lane][8];
            #pragma unroll
            for (int i = 0; i < 2; ++i) {
                if (i < c3) {
                    const int nt = (i == 0) ? wv : 8;
                    const unsigned short* wp = w3f + ((size_t)(nt * 6 + kt) * 64 + lane) * 16;
                    bf16x8 bh = *(const bf16x8*)wp;
                    bf16x8 bl = *(const bf16x8*)(wp + 8);
                    acc[i] = __builtin_amdgcn_mfma_f32_16x16x32_bf16(bh, axh, acc[i], 0, 0, 0);
                    acc[i] = __builtin_amdgcn_mfma_f32_16x16x32_bf16(bl, axh, acc[i], 0, 0, 0);
                    acc[i] = __builtin_amdgcn_mfma_f32_16x16x32_bf16(bh, axl, acc[i], 0, 0, 0);
                }
            }
        }
        float ssq = 0.f;
        float pred = 0.f, tgt = 0.f;
        #pragma unroll
        for (int i = 0; i < 2; ++i) {
            if (i < c3) {
                const int ntg = (i == 0) ? wv : 8;
                const int n0 = ntg * 16 + lg * 4;
                f32x4 bv = *(const f32x4*)(b3c + n0);
                f32x4 v = acc[i] + bv;
                if (ntg == 0) {
                    if (lg == 0) { pred = v.x; tgt = v.y; }
                } else {
                    ushort4v zu;
                    #pragma unroll
                    for (int r = 0; r < 4; ++r) {
                        unsigned short us = f32_to_bf16_rne(v[r]);
                        float zf32 = __uint_as_float(((unsigned int)us) << 16);
                        ssq += zf32 * zf32;
                        zu[r] = us;
                    }
                    const int ch = (ntg - 1) * 2 + (lg >> 1);
                    const int kk = ch >> 2;
                    const int lane2 = (ch & 3) * 16 + l15;
                    const int e0 = (lg & 1) * 4;
                    *(ushort4v*)(zf + ((size_t)(mt * 4 + kk) * 64 + lane2) * 8 + e0) = zu;
                }
            }
        }
        ssq += __shfl_xor(ssq, 16);
        ssq += __shfl_xor(ssq, 32);
        if (lg == 0) sred[wv][l15] = ssq;
        __syncthreads();
        if (t < 16) {
            float sm = 0.f;
            #pragma unroll
            for (int w8 = 0; w8 < 8; ++w8) sm += sred[w8][t];
            sq[mt * 16 + t] = sm;
        }
        if (wv == 0 && lg == 0) {
            float d = pred - tgt;
            alpha[mt * 16 + l15] = d * d;
        }
    }
}

// ---------------- K1b: threshold pre-pass — 11th-smallest key vs 512-row sample ----------------
// 128 blocks x 256 thr; wave = 1 q-tile (16 queries) x 512 sample candidates.
__global__ __launch_bounds__(256, 4) void k_thr(
    const unsigned short* __restrict__ zf, const float* __restrict__ sq,
    float* __restrict__ thrA)
{
    __shared__ float buf[4][64][BCAP];
    __shared__ float sqs[512];
    const int t = threadIdx.x;
    const int lane = t & 63, wv = t >> 6;
    const int qt16 = blockIdx.x * 4 + wv;   // 512 q-tiles
    const int l15 = lane & 15, lg = lane >> 4;

    sqs[t] = sq[t];
    sqs[t + 256] = sq[t + 256];
    __syncthreads();

    float* bp = &buf[wv][lane][0];
    const int qid = qt16 * 16 + l15;
    bf16x8 bq[4];
    {
        const unsigned short* qp = zf + ((size_t)qt16 * 256 + lane) * 8;
        #pragma unroll
        for (int kk = 0; kk < 4; ++kk) bq[kk] = *(const bf16x8*)(qp + kk * 512);
    }

    float vals[K2];
    #pragma unroll
    for (int i = 0; i < K2; ++i) vals[i] = BIGF;
    float thr = BIGF;
    int cnt = 0;

    const unsigned short* zcl = zf + (size_t)lane * 8;
    bf16x8 av[4];
    #pragma unroll
    for (int kk = 0; kk < 4; ++kk) av[kk] = *(const bf16x8*)(zcl + kk * 512);

    for (int tile = 0; tile < 32; ++tile) {
        f32x4 acc = {0.f, 0.f, 0.f, 0.f};
        #pragma unroll
        for (int kk = 0; kk < 4; ++kk)
            acc = __builtin_amdgcn_mfma_f32_16x16x32_bf16(av[kk], bq[kk], acc, 0, 0, 0);
        if (tile < 31) {
            const unsigned short* p = zcl + (size_t)(tile + 1) * 2048;
            #pragma unroll
            for (int kk = 0; kk < 4; ++kk) av[kk] = *(const bf16x8*)(p + kk * 512);
        }
        f32x4 sqv = *(const f32x4*)(&sqs[tile * 16 + lg * 4]);
        #pragma unroll
        for (int r = 0; r < 4; ++r) {
            float v = fmaf(-2.0f, acc[r], sqv[r]);
            bp[cnt] = v;
            cnt += (int)(v <= thr);
        }
        if (__any(cnt >= TRIG)) { compactB(vals, bp, cnt); thr = vals[K2 - 1]; cnt = 0; }
    }
    compactB(vals, bp, cnt);

    float wk[K2];
    #pragma unroll
    for (int i = 0; i < K2; ++i) {
        float o = __shfl_xor(vals[K2 - 1 - i], 16);
        wk[i] = fminf(vals[i], o);
    }
    sortBitonic11(wk);
    float m1[K2];
    #pragma unroll
    for (int i = 0; i < K2; ++i) {
        float o = __shfl_xor(wk[K2 - 1 - i], 32);
        m1[i] = fminf(wk[i], o);
    }
    // m1 is bitonic; its max (the 11th smallest) = max of the two "peak" candidates
    if (lg == 0) {
        float mx = m1[0];
        #pragma unroll
        for (int i = 1; i < K2; ++i) mx = fmaxf(mx, m1[i]);
        thrA[qid] = mx;
    }
}

// ---------------- K2: pairwise + sample-thresholded top-11 ----------------
// 1024 blocks x 256 thr; split = b&15, qg = (b>>4)*4 + wave; 32 queries x 512 cands.
// thr0/thr1 from k_thr: provably >= true 11th key -> accept with <=, never loses a winner.
__global__ __launch_bounds__(256, 4) void k_pairs(
    const unsigned short* __restrict__ zf, const float* __restrict__ sq,
    const float* __restrict__ thrA, float* __restrict__ part)
{
    __shared__ float buf[4][2][64][BCAP];
    __shared__ float sqs[512];
    const int t = threadIdx.x;
    const int lane = t & 63;
    const int wv = t >> 6;
    const int split = blockIdx.x & 15;
    const int qg = (blockIdx.x >> 4) * 4 + wv;
    const int l15 = lane & 15, lg = lane >> 4;
    const int c0 = split * 512;

    sqs[t] = sq[c0 + t];
    sqs[t + 256] = sq[c0 + t + 256];
    __syncthreads();

    float* bp0 = &buf[wv][0][lane][0];
    float* bp1 = &buf[wv][1][lane][0];

    const int qid0 = qg * 32 + l15;
    const int qid1 = qg * 32 + 16 + l15;
    bf16x8 bq[2][4];
    {
        const unsigned short* qp0 = zf + ((size_t)(qg * 2) * 256 + lane) * 8;
        const unsigned short* qp1 = zf + ((size_t)(qg * 2 + 1) * 256 + lane) * 8;
        #pragma unroll
        for (int kk = 0; kk < 4; ++kk) {
            bq[0][kk] = *(const bf16x8*)(qp0 + kk * 512);
            bq[1][kk] = *(const bf16x8*)(qp1 + kk * 512);
        }
    }
    float thr0 = thrA[qid0];
    float thr1 = thrA[qid1];

    float vals[2][K2];
    #pragma unroll
    for (int qt = 0; qt < 2; ++qt)
        #pragma unroll
        for (int i = 0; i < K2; ++i) vals[qt][i] = BIGF;
    int cnt0 = 0, cnt1 = 0;

    const unsigned short* zcl = zf + ((size_t)(split * 32) * 256 + lane) * 8;
    bf16x8 avA[4], avB[4];
    #pragma unroll
    for (int kk = 0; kk < 4; ++kk) avA[kk] = *(const bf16x8*)(zcl + kk * 512);
    #pragma unroll
    for (int kk = 0; kk < 4; ++kk) avB[kk] = *(const bf16x8*)(zcl + 2048 + kk * 512);

    for (int tile = 0; tile < 32; tile += 2) {
        {
            f32x4 acc0 = {0.f,0.f,0.f,0.f}, acc1 = {0.f,0.f,0.f,0.f};
            #pragma unroll
            for (int kk = 0; kk < 4; ++kk) {
                acc0 = __builtin_amdgcn_mfma_f32_16x16x32_bf16(avA[kk], bq[0][kk], acc0, 0, 0, 0);
                acc1 = __builtin_amdgcn_mfma_f32_16x16x32_bf16(avA[kk], bq[1][kk], acc1, 0, 0, 0);
            }
            if (tile + 2 < 32) {
                const unsigned short* p = zcl + (size_t)(tile + 2) * 2048;
                #pragma unroll
                for (int kk = 0; kk < 4; ++kk) avA[kk] = *(const bf16x8*)(p + kk * 512);
            }
            f32x4 sqv = *(const f32x4*)(&sqs[tile * 16 + lg * 4]);
            #pragma unroll
            for (int r = 0; r < 4; ++r) {
                float v0 = fmaf(-2.0f, acc0[r], sqv[r]);
                bp0[cnt0] = v0;
                cnt0 += (int)(v0 <= thr0);
                float v1 = fmaf(-2.0f, acc1[r], sqv[r]);
                bp1[cnt1] = v1;
                cnt1 += (int)(v1 <= thr1);
            }
            if (__any(cnt0 >= TRIG)) { compactB(vals[0], bp0, cnt0); thr0 = fminf(thr0, vals[0][K2 - 1]); cnt0 = 0; }
            if (__any(cnt1 >= TRIG)) { compactB(vals[1], bp1, cnt1); thr1 = fminf(thr1, vals[1][K2 - 1]); cnt1 = 0; }
        }
        {
            f32x4 acc0 = {0.f,0.f,0.f,0.f}, acc1 = {0.f,0.f,0.f,0.f};
            #pragma unroll
            for (int kk = 0; kk < 4; ++kk) {
                acc0 = __builtin_amdgcn_mfma_f32_16x16x32_bf16(avB[kk], bq[0][kk], acc0, 0, 0, 0);
                acc1 = __builtin_amdgcn_mfma_f32_16x16x32_bf16(avB[kk], bq[1][kk], acc1, 0, 0, 0);
            }
            if (tile + 3 < 32) {
                const unsigned short* p = zcl + (size_t)(tile + 3) * 2048;
                #pragma unroll
                for (int kk = 0; kk < 4; ++kk) avB[kk] = *(const bf16x8*)(p + kk * 512);
            }
            f32x4 sqv = *(const f32x4*)(&sqs[(tile + 1) * 16 + lg * 4]);
            #pragma unroll
            for (int r = 0; r < 4; ++r) {
                float v0 = fmaf(-2.0f, acc0[r], sqv[r]);
                bp0[cnt0] = v0;
                cnt0 += (int)(v0 <= thr0);
                float v1 = fmaf(-2.0f, acc1[r], sqv[r]);
                bp1[cnt1] = v1;
                cnt1 += (int)(v1 <= thr1);
            }
            if (__any(cnt0 >= TRIG)) { compactB(vals[0], bp0, cnt0); thr0 = fminf(thr0, vals[0][K2 - 1]); cnt0 = 0; }
            if (__any(cnt1 >= TRIG)) { compactB(vals[1], bp1, cnt1); thr1 = fminf(thr1, vals[1][K2 - 1]); cnt1 = 0; }
        }
    }
    compactB(vals[0], bp0, cnt0);
    compactB(vals[1], bp1, cnt1);

    #pragma unroll
    for (int qt = 0; qt < 2; ++qt) {
        float wk[K2];
        #pragma unroll
        for (int i = 0; i < K2; ++i) {
            float o = __shfl_xor(vals[qt][K2 - 1 - i], 16);
            wk[i] = fminf(vals[qt][i], o);
        }
        sortBitonic11(wk);
        float m1[K2];
        #pragma unroll
        for (int i = 0; i < K2; ++i) {
            float o = __shfl_xor(wk[K2 - 1 - i], 32);
            m1[i] = fminf(wk[i], o);
        }
        if (lg == 0) {
            const int qid = (qt == 0) ? qid0 : qid1;
            float* dst = part + ((size_t)split * NROWS + qid) * K2;
            #pragma unroll
            for (int i = 0; i < K2; ++i) dst[i] = m1[i];
        }
    }
}

// ---------------- K3: merge 16 partial 11-lists (2 threads/q); drop min (self) ----------------
__global__ __launch_bounds__(256) void k_merge(
    const float* __restrict__ part, const float* __restrict__ sq,
    float* __restrict__ sumk, float* __restrict__ total)
{
    __shared__ float xb[128][K2 + 1];
    __shared__ float red[4];
    const int t = threadIdx.x;
    const int qi = t & 127, hf = t >> 7;
    const int q = blockIdx.x * 128 + qi;

    float vals[K2];
    #pragma unroll
    for (int i = 0; i < K2; ++i) vals[i] = BIGF;
    for (int seg = hf * 8; seg < hf * 8 + 8; ++seg) {
        const float* p = part + ((size_t)seg * NROWS + q) * K2;
        #pragma unroll
        for (int i = 0; i < K2; ++i) {
            float tv = p[i];
            if (tv < vals[K2 - 1]) insert11(vals, tv);
        }
    }
    if (hf) {
        #pragma unroll
        for (int i = 0; i < K2; ++i) xb[qi][i] = vals[i];
    }
    __syncthreads();
    float sum = 0.f;
    if (!hf) {
        #pragma unroll
        for (int i = 0; i < K2; ++i) {
            float tv = xb[qi][i];
            if (tv < vals[K2 - 1]) insert11(vals, tv);
        }
        float sqq = sq[q];
        #pragma unroll
        for (int i = 1; i < K2; ++i) {
            float raw = sqq + vals[i];
            sum += (raw > 0.f) ? sqrtf(raw) : 0.f;
        }
        sumk[q] = sum;
    }
    #pragma unroll
    for (int off = 32; off > 0; off >>= 1) sum += __shfl_down(sum, off);
    if ((t & 63) == 0) red[t >> 6] = sum;
    __syncthreads();
    if (t == 0) atomicAdd(total, red[0] + red[1] + red[2] + red[3]);
}

// ---------------- K4: finalize ----------------
__global__ __launch_bounds__(256) void k_final(
    const float* __restrict__ sumk, const float* __restrict__ alpha,
    const float* __restrict__ total, float* __restrict__ out)
{
    const int q = blockIdx.x * 256 + threadIdx.x;
    float mean = (*total) * (1.0f / NROWS);
    float m2 = mean * mean;
    float sk = sumk[q];
    float x = (sk * sk) / m2;
    float knn = EPS_CONST / (x + EPS_CONST);
    float rep = 1.0f / (sqrtf(knn) + C_CONST);
    float a = alpha[q];
    a = fminf(fmaxf(a, 1.0f), L_CONST);
    out[q] = rep * a;
}

extern "C" void kernel_launch(void* const* d_in, const int* in_sizes, int n_in,
                              void* d_out, int out_size, void* d_ws, size_t ws_size,
                              hipStream_t stream) {
    const float* s   = (const float*)d_in[0];
    const float* w1  = (const float*)d_in[1];
    const float* b1  = (const float*)d_in[2];
    const float* w2  = (const float*)d_in[3];
    const float* b2  = (const float*)d_in[4];
    const float* w3  = (const float*)d_in[5];
    const float* b3  = (const float*)d_in[6];
    const float* wt1 = (const float*)d_in[7];
    const float* bt1 = (const float*)d_in[8];
    const float* wt2 = (const float*)d_in[9];
    const float* bt2 = (const float*)d_in[10];
    const float* wt3 = (const float*)d_in[11];
    const float* bt3 = (const float*)d_in[12];
    const float* wz1 = (const float*)d_in[13];
    const float* bz1 = (const float*)d_in[14];
    const float* wz2 = (const float*)d_in[15];
    const float* bz2 = (const float*)d_in[16];
    const float* wz3 = (const float*)d_in[17];
    const float* bz3 = (const float*)d_in[18];

    char* ws = (char*)d_ws;
    unsigned short* zf  = (unsigned short*)(ws);                // 2097152
    float* sq    = (float*)(ws + 2097152);                      // 32768
    float* alpha = (float*)(ws + 2129920);                      // 32768
    float* part  = (float*)(ws + 2162688);                      // 5767168
    float* sumk  = (float*)(ws + 7929856);                      // 32768
    float* total = (float*)(ws + 7962624);                      // 256
    float* thrA  = (float*)(ws + 7962880);                      // 32768
    unsigned short* w1f = (unsigned short*)(ws + 7995648);      // 786432
    unsigned short* w2f = (unsigned short*)(ws + 8782080);      // 294912
    unsigned short* w3f = (unsigned short*)(ws + 9076992);      // 110592
    float* b1c = (float*)(ws + 9187584);
    float* b2c = (float*)(ws + 9189120);
    float* b3c = (float*)(ws + 9189888);

    hipMemsetAsync(total, 0, sizeof(float), stream);

    k_prepw<<<147, 256, 0, stream>>>(w1, wt1, wz1, w2, wt2, wz2, w3, wt3, wz3,
                                     b1, bt1, bz1, b2, bt2, bz2, b3, bt3, bz3,
                                     w1f, w2f, w3f, b1c, b2c, b3c);
    k_mlp<<<512, 512, 0, stream>>>(s, w1f, w2f, w3f, b1c, b2c, b3c, zf, sq, alpha);
    k_thr<<<128, 256, 0, stream>>>(zf, sq, thrA);
    k_pairs<<<1024, 256, 0, stream>>>(zf, sq, thrA, part);
    k_merge<<<64, 256, 0, stream>>>(part, sq, sumk, total);
    k_final<<<32, 256, 0, stream>>>(sumk, alpha, total, (float*)d_out);
}